// Round 5
// baseline (749.802 us; speedup 1.0000x reference)
//
#include <hip/hip_runtime.h>
#include <stdint.h>

typedef unsigned short u16;
typedef unsigned int u32;
typedef unsigned long long u64;

typedef __attribute__((ext_vector_type(8))) __bf16 bf16x8;
typedef __attribute__((ext_vector_type(4))) float f32x4;

#define NROW 8192
#define DMODEL 256
#define HD 64
#define LDT 72   // LDS row stride (u16) for k_qkv/k_prep tiles

__device__ __forceinline__ u16 f2bf(float f) {   // RNE f32 -> bf16
    u32 u = __builtin_bit_cast(u32, f);
    u += 0x7FFFu + ((u >> 16) & 1u);
    return (u16)(u >> 16);
}
__device__ __forceinline__ bf16x8 ldb8(const u16* p) {
    uint4 v = *(const uint4*)p;
    return __builtin_bit_cast(bf16x8, v);
}
__device__ __forceinline__ f32x4 mfma16(bf16x8 a, bf16x8 b, f32x4 c) {
    return __builtin_amdgcn_mfma_f32_16x16x32_bf16(a, b, c, 0, 0, 0);
}

// ---------------- kernel P: x f32->bf16 ; W f32->bf16 transposed -----------
__global__ __launch_bounds__(256) void k_prep(
    const float* __restrict__ x,
    const float* __restrict__ Wq, const float* __restrict__ Wk,
    const float* __restrict__ Wv,
    u16* __restrict__ xb, u16* __restrict__ Wt) {
    const int t = threadIdx.x;
    if (blockIdx.x < 1024) {                       // x convert: 8 elems/thread
        size_t idx = (size_t)blockIdx.x * 2048 + t * 8;
        f32x4 a = *(const f32x4*)&x[idx];
        f32x4 b = *(const f32x4*)&x[idx + 4];
        uint4 o;
        o.x = (u32)f2bf(a[0]) | ((u32)f2bf(a[1]) << 16);
        o.y = (u32)f2bf(a[2]) | ((u32)f2bf(a[3]) << 16);
        o.z = (u32)f2bf(b[0]) | ((u32)f2bf(b[1]) << 16);
        o.w = (u32)f2bf(b[2]) | ((u32)f2bf(b[3]) << 16);
        *(uint4*)&xb[idx] = o;
        return;
    }
    // W transpose: 48 blocks, 64x64 tiles
    __shared__ __align__(16) u16 lw[64 * LDT];
    int wb = blockIdx.x - 1024;
    int mat = wb >> 4, tile = wb & 15;
    int k0 = (tile >> 2) * 64, n0 = (tile & 3) * 64;
    const float* W = (mat == 0) ? Wq : ((mat == 1) ? Wk : Wv);
    #pragma unroll
    for (int i = 0; i < 4; ++i) {
        int c = t + 256 * i;
        int k = c >> 4, c4 = c & 15;
        f32x4 w4 = *(const f32x4*)&W[(size_t)(k0 + k) * DMODEL + n0 + c4 * 4];
        uint2 pk;
        pk.x = (u32)f2bf(w4[0]) | ((u32)f2bf(w4[1]) << 16);
        pk.y = (u32)f2bf(w4[2]) | ((u32)f2bf(w4[3]) << 16);
        *(uint2*)&lw[k * LDT + c4 * 4] = pk;
    }
    __syncthreads();
    #pragma unroll
    for (int i = 0; i < 2; ++i) {
        int c = t + 256 * i;
        int n = c >> 3, k8 = c & 7;
        union { uint4 u; u16 s[8]; } pk;
        #pragma unroll
        for (int j = 0; j < 8; ++j) pk.s[j] = lw[(k8 * 8 + j) * LDT + n];
        *(uint4*)&Wt[(size_t)mat * 65536 + (size_t)(n0 + n) * DMODEL + k0 + k8 * 8] = pk.u;
    }
}

// ---------------- kernel 0: edge -> PERMUTED bitmask ------------------------
// pbits[(q*4+c)*8192 + m], bit L = (edge[m][q*256 + 4L + c] != 0)
// dwordx4 loads (coalesced 1KB/instr); stores staged in LDS -> 64B-coalesced.
__global__ __launch_bounds__(256, 4) void k_bitmask(const int* __restrict__ edge,
                                                    u64* __restrict__ pbits) {
    __shared__ u64 lb[128][8];                     // [q*4+c][local row] 8KB
    const int t = threadIdx.x;
    const int lane = t & 63, w = t >> 6;
    const u32 m8 = blockIdx.x * 8u;
    #pragma unroll
    for (int rr = 0; rr < 2; ++rr) {
        const int mloc = w * 2 + rr;
        const size_t base = (size_t)(m8 + mloc) * NROW;
        for (int q0 = 0; q0 < 32; q0 += 4) {
            int4 e[4];
            #pragma unroll
            for (int j = 0; j < 4; ++j)
                e[j] = *(const int4*)&edge[base + (size_t)(q0 + j) * 256 + lane * 4];
            #pragma unroll
            for (int j = 0; j < 4; ++j) {
                u64 b0 = __ballot(e[j].x != 0);
                u64 b1 = __ballot(e[j].y != 0);
                u64 b2 = __ballot(e[j].z != 0);
                u64 b3 = __ballot(e[j].w != 0);
                if (lane == 0) {
                    lb[(q0 + j) * 4 + 0][mloc] = b0;
                    lb[(q0 + j) * 4 + 1][mloc] = b1;
                    lb[(q0 + j) * 4 + 2][mloc] = b2;
                    lb[(q0 + j) * 4 + 3][mloc] = b3;
                }
            }
        }
    }
    __syncthreads();
    const int qc = t >> 1, r0 = (t & 1) * 4;       // 4 u64 per thread
    uint4 a = *(uint4*)&lb[qc][r0];
    uint4 b = *(uint4*)&lb[qc][r0 + 2];
    *(uint4*)&pbits[(size_t)qc * NROW + m8 + r0] = a;
    *(uint4*)&pbits[(size_t)qc * NROW + m8 + r0 + 2] = b;
}

// ---------------- kernel 1: QKV projections (bf16 in -> bf16 out) ----------
__global__ __launch_bounds__(256, 3) void k_qkv(
    const u16* __restrict__ xb, const u16* __restrict__ Wt,
    const float* __restrict__ bq, const float* __restrict__ bk,
    const float* __restrict__ bv,
    u16* __restrict__ Qo, u16* __restrict__ Ko, u16* __restrict__ Vt) {
    __shared__ __align__(16) u16 ax[128 * LDT];
    __shared__ __align__(16) u16 wt[64 * LDT];
    const int t = threadIdx.x;
    const int lane = t & 63, wv = t >> 6;
    const int q4 = lane >> 4, l15 = lane & 15;
    const int wr = wv >> 1, wc = wv & 1;
    const int row0 = blockIdx.x * 128;
    const int mat = blockIdx.y >> 2;
    const int c0 = (blockIdx.y & 3) * 64;
    const u16* Wm = Wt + (size_t)mat * 65536;
    const float* bias = (mat == 0) ? bq : ((mat == 1) ? bk : bv);

    f32x4 acc[8];
    #pragma unroll
    for (int i = 0; i < 8; ++i) acc[i] = {0.f, 0.f, 0.f, 0.f};

    for (int kk = 0; kk < DMODEL; kk += 64) {
        #pragma unroll
        for (int i = 0; i < 4; ++i) {
            int c = t + 256 * i;
            int row = c >> 3, c8 = c & 7;
            *(uint4*)&ax[row * LDT + c8 * 8] =
                *(const uint4*)&xb[(size_t)(row0 + row) * DMODEL + kk + c8 * 8];
        }
        #pragma unroll
        for (int i = 0; i < 2; ++i) {
            int c = t + 256 * i;
            int n = c >> 3, c8 = c & 7;
            *(uint4*)&wt[n * LDT + c8 * 8] =
                *(const uint4*)&Wm[(size_t)(c0 + n) * DMODEL + kk + c8 * 8];
        }
        __syncthreads();
        #pragma unroll
        for (int ks = 0; ks < 2; ++ks) {
            bf16x8 xf[4], wf[2];
            #pragma unroll
            for (int it = 0; it < 4; ++it)
                xf[it] = ldb8(&ax[(wr * 64 + it * 16 + l15) * LDT + ks * 32 + q4 * 8]);
            #pragma unroll
            for (int jt = 0; jt < 2; ++jt)
                wf[jt] = ldb8(&wt[(wc * 32 + jt * 16 + l15) * LDT + ks * 32 + q4 * 8]);
            if (mat < 2) {
                #pragma unroll
                for (int it = 0; it < 4; ++it)
                    #pragma unroll
                    for (int jt = 0; jt < 2; ++jt)
                        acc[it * 2 + jt] = mfma16(xf[it], wf[jt], acc[it * 2 + jt]);
            } else {
                #pragma unroll
                for (int jt = 0; jt < 2; ++jt)
                    #pragma unroll
                    for (int it = 0; it < 4; ++it)
                        acc[jt * 4 + it] = mfma16(wf[jt], xf[it], acc[jt * 4 + it]);
            }
        }
        __syncthreads();
    }

    if (mat < 2) {
        u16* out = (mat == 0) ? Qo : Ko;
        const float scale = (mat == 0) ? 0.18033688f : 1.0f;  // 0.125*log2(e)
        #pragma unroll
        for (int jt = 0; jt < 2; ++jt) {
            int col = c0 + wc * 32 + jt * 16 + l15;
            float bcol = bias[col];
            #pragma unroll
            for (int it = 0; it < 4; ++it) {
                int rowb = row0 + wr * 64 + it * 16 + q4 * 4;
                f32x4 a = acc[it * 2 + jt];
                #pragma unroll
                for (int r = 0; r < 4; ++r)
                    out[(size_t)(rowb + r) * DMODEL + col] = f2bf((a[r] + bcol) * scale);
            }
        }
    } else {
        #pragma unroll
        for (int jt = 0; jt < 2; ++jt) {
            #pragma unroll
            for (int r = 0; r < 4; ++r) {
                int drow = c0 + wc * 32 + jt * 16 + q4 * 4 + r;
                float bd = bias[drow];
                #pragma unroll
                for (int it = 0; it < 4; ++it) {
                    int col = row0 + wr * 64 + it * 16 + l15;
                    Vt[(size_t)drow * NROW + col] = f2bf(acc[jt * 4 + it][r] + bd);
                }
            }
        }
    }
}

// ---------------- kernel 2: flash attention (R3 structure, swizzled LDS) ----
// grid 512: h=(bid>>1)&3, qt=((bid>>3)<<1)|(bid&1); 4 waves x 16 Q-rows (n).
// Rounds of BN=128 (two 64-m halves, software-pipelined). XOR-swizzled LDS:
// sK/sP rows 128B (8 chunks, c^=row&7); sV rows 256B (16 chunks, c^=d&15).
// Permuted mask bits; no-max softmax in exp2 domain; l via ones-MFMA.
__global__ __launch_bounds__(256, 2) void k_attn(
    const u16* __restrict__ Q, const u16* __restrict__ K,
    const u16* __restrict__ Vt, const u64* __restrict__ pbits,
    float* __restrict__ out) {
    __shared__ __align__(16) u16 sK[128 * 64];     // 128 m x 64 d, swizzled (16KB)
    __shared__ __align__(16) u16 sV[64 * 128];     // 64 d x 128 m, swizzled (16KB)
    __shared__ __align__(16) u16 sP[4][2][16 * 64];// per-wave/half P: 16 n x 64 m (16KB)
    __shared__ __align__(16) u32 sB[4][132];       // permuted mask words [c][m]

    const int t = threadIdx.x;
    const int lane = t & 63, w = t >> 6;
    const int q4 = lane >> 4, l15 = lane & 15;
    const int l7 = l15 & 7;
    const int bid = blockIdx.x;
    const int h = (bid >> 1) & 3;
    const int qt = ((bid >> 3) << 1) | (bid & 1);
    const int n0 = qt * 64;
    const int halfsel = (qt >> 1) & 1;             // u32 half of the u64 ballot word
    const int shiftv = ((((qt & 3) * 16 + w * 4) & 31)) + (l15 >> 2);
    const int qbase = (qt >> 2) * 4;               // pbits row group

    // staging coords
    const int krow = t >> 3, kc = t & 7;           // sK: rows +32/i
    const int vd = t >> 4, vc = t & 15;            // sV: d-rows +16/i
    const int bc = t >> 6, bm = t & 63;            // sB: c, m

    bf16x8 qf[2];
    #pragma unroll
    for (int ks = 0; ks < 2; ++ks)
        qf[ks] = ldb8(&Q[(size_t)(n0 + w * 16 + l15) * DMODEL + h * HD + ks * 32 + q4 * 8]);

    uint4 onesu = {0x3F803F80u, 0x3F803F80u, 0x3F803F80u, 0x3F803F80u};
    const bf16x8 ones = __builtin_bit_cast(bf16x8, onesu);

    f32x4 o[4], lacc;
    lacc = {0.f, 0.f, 0.f, 0.f};
    #pragma unroll
    for (int dt = 0; dt < 4; ++dt) o[dt] = {0.f, 0.f, 0.f, 0.f};

    const u32* pb32 = (const u32*)pbits;
    uint4 rk[4], rv[4]; u32 rb[2];
    #pragma unroll
    for (int i = 0; i < 4; ++i) {                  // prefetch round 0
        rk[i] = *(const uint4*)&K[(size_t)(i * 32 + krow) * DMODEL + h * HD + kc * 8];
        rv[i] = *(const uint4*)&Vt[(size_t)(h * HD + i * 16 + vd) * NROW + vc * 8];
    }
    #pragma unroll
    for (int i = 0; i < 2; ++i)
        rb[i] = pb32[((size_t)(qbase + bc) * NROW + i * 64 + bm) * 2 + halfsel];

    for (int kt = 0; kt < 64; ++kt) {
        __syncthreads();                           // prev round's reads done
        #pragma unroll
        for (int i = 0; i < 4; ++i) {              // commit (swizzled)
            *(uint4*)&sK[(i * 32 + krow) * 64 + ((kc ^ (krow & 7)) * 8)] = rk[i];
            *(uint4*)&sV[(i * 16 + vd) * 128 + ((vc ^ vd) * 8)] = rv[i];
        }
        sB[bc][bm] = rb[0];
        sB[bc][64 + bm] = rb[1];
        __syncthreads();

        if (kt < 63) {                             // prefetch next round
            int m0n = (kt + 1) * 128;
            #pragma unroll
            for (int i = 0; i < 4; ++i) {
                rk[i] = *(const uint4*)&K[(size_t)(m0n + i * 32 + krow) * DMODEL + h * HD + kc * 8];
                rv[i] = *(const uint4*)&Vt[(size_t)(h * HD + i * 16 + vd) * NROW + m0n + vc * 8];
            }
            #pragma unroll
            for (int i = 0; i < 2; ++i)
                rb[i] = pb32[((size_t)(qbase + bc) * NROW + m0n + i * 64 + bm) * 2 + halfsel];
        }

        // --- S + exp2 + P-pack for both halves (pipelined) ---
        #pragma unroll
        for (int half = 0; half < 2; ++half) {
            f32x4 s[4];
            #pragma unroll
            for (int tj = 0; tj < 4; ++tj) s[tj] = {0.f, 0.f, 0.f, 0.f};
            #pragma unroll
            for (int ks = 0; ks < 2; ++ks) {
                #pragma unroll
                for (int tj = 0; tj < 4; ++tj) {
                    bf16x8 kb = ldb8(&sK[(half * 64 + tj * 16 + l15) * 64 +
                                         (((ks * 4 + q4) ^ l7) * 8)]);
                    s[tj] = mfma16(kb, qf[ks], s[tj]);
                }
            }
            #pragma unroll
            for (int tj = 0; tj < 4; ++tj) {
                uint4 bw = *(const uint4*)&sB[l15 & 3][half * 64 + tj * 16 + q4 * 4];
                u32 wd[4] = {bw.x, bw.y, bw.z, bw.w};
                u32 ub[4];
                #pragma unroll
                for (int r = 0; r < 4; ++r) {
                    float sv = ((wd[r] >> shiftv) & 1u) ? s[tj][r] : -1e30f;
                    ub[r] = __builtin_bit_cast(u32, __builtin_amdgcn_exp2f(sv));
                }
                uint2 pk;
                pk.x = (ub[0] >> 16) | (ub[1] & 0xFFFF0000u);
                pk.y = (ub[2] >> 16) | (ub[3] & 0xFFFF0000u);
                *(uint2*)&sP[w][half][l15 * 64 +
                                      (((tj * 2 + (q4 >> 1)) ^ l7) * 8) + (q4 & 1) * 4] = pk;
            }
        }
        asm volatile("s_waitcnt lgkmcnt(0)" ::: "memory");  // sP is wave-private

        // --- PV for both halves ---
        #pragma unroll
        for (int half = 0; half < 2; ++half) {
            #pragma unroll
            for (int ks = 0; ks < 2; ++ks) {
                bf16x8 pf = ldb8(&sP[w][half][l15 * 64 + (((ks * 4 + q4) ^ l7) * 8)]);
                #pragma unroll
                for (int dt = 0; dt < 4; ++dt) {
                    bf16x8 vb = ldb8(&sV[(dt * 16 + l15) * 128 +
                                         (((half * 8 + ks * 4 + q4) ^ l15) * 8)]);
                    o[dt] = mfma16(pf, vb, o[dt]);
                }
                lacc = mfma16(pf, ones, lacc);
            }
        }
    }

    #pragma unroll
    for (int r = 0; r < 4; ++r) {
        float inv = __builtin_amdgcn_rcpf(lacc[r] + 1e-30f);
        int n = n0 + w * 16 + q4 * 4 + r;
        #pragma unroll
        for (int dt = 0; dt < 4; ++dt)
            out[(size_t)n * DMODEL + h * HD + dt * 16 + l15] = o[dt][r] * inv;
    }
}

extern "C" void kernel_launch(void* const* d_in, const int* in_sizes, int n_in,
                              void* d_out, int out_size, void* d_ws, size_t ws_size,
                              hipStream_t stream) {
    const float* x  = (const float*)d_in[0];
    const int* edge = (const int*)d_in[1];
    const float* Wq = (const float*)d_in[2];
    const float* bq = (const float*)d_in[3];
    const float* Wk = (const float*)d_in[4];
    const float* bk = (const float*)d_in[5];
    const float* Wv = (const float*)d_in[6];
    const float* bv = (const float*)d_in[7];

    char* ws = (char*)d_ws;
    u64* pbits = (u64*)ws;                       //  8 MB (permuted bitmask)
    u16* Qo  = (u16*)(ws + (8u << 20));          //  4 MB (bf16, Q pre-scaled)
    u16* Ko  = (u16*)(ws + (12u << 20));         //  4 MB (bf16)
    u16* Vt  = (u16*)(ws + (16u << 20));         //  4 MB (bf16, [256][8192])
    u16* xb  = (u16*)(ws + (20u << 20));         //  4 MB (bf16 x)
    u16* Wt  = (u16*)(ws + (24u << 20));         //  384 KB (bf16, 3x[256n][256k])
    float* out = (float*)d_out;

    hipLaunchKernelGGL(k_prep, dim3(1072), dim3(256), 0, stream, x, Wq, Wk, Wv, xb, Wt);
    hipLaunchKernelGGL(k_bitmask, dim3(1024), dim3(256), 0, stream, edge, pbits);
    hipLaunchKernelGGL(k_qkv, dim3(64, 12), dim3(256), 0, stream,
                       xb, Wt, bq, bk, bv, Qo, Ko, Vt);
    hipLaunchKernelGGL(k_attn, dim3(512), dim3(256), 0, stream, Qo, Ko, Vt, pbits, out);
}

// Round 6
// 536.420 us; speedup vs baseline: 1.3978x; 1.3978x over previous
//
#include <hip/hip_runtime.h>
#include <stdint.h>

typedef unsigned short u16;
typedef unsigned int u32;
typedef unsigned long long u64;

typedef __attribute__((ext_vector_type(8))) __bf16 bf16x8;
typedef __attribute__((ext_vector_type(4))) float f32x4;

#define NROW 8192
#define DMODEL 256
#define HD 64
#define LDT 72   // LDS row stride (u16): 144 B = 9*16B aligned

__device__ __forceinline__ u16 f2bf(float f) {   // RNE f32 -> bf16
    u32 u = __builtin_bit_cast(u32, f);
    u += 0x7FFFu + ((u >> 16) & 1u);
    return (u16)(u >> 16);
}
__device__ __forceinline__ bf16x8 ldb8(const u16* p) {
    uint4 v = *(const uint4*)p;
    return __builtin_bit_cast(bf16x8, v);
}
__device__ __forceinline__ f32x4 mfma16(bf16x8 a, bf16x8 b, f32x4 c) {
    return __builtin_amdgcn_mfma_f32_16x16x32_bf16(a, b, c, 0, 0, 0);
}

// ---------------- kernel P: x f32->bf16 ; W f32->bf16 transposed -----------
__global__ __launch_bounds__(256) void k_prep(
    const float* __restrict__ x,
    const float* __restrict__ Wq, const float* __restrict__ Wk,
    const float* __restrict__ Wv,
    u16* __restrict__ xb, u16* __restrict__ Wt) {
    const int t = threadIdx.x;
    if (blockIdx.x < 1024) {                       // x convert: 8 elems/thread
        size_t idx = (size_t)blockIdx.x * 2048 + t * 8;
        f32x4 a = *(const f32x4*)&x[idx];
        f32x4 b = *(const f32x4*)&x[idx + 4];
        uint4 o;
        o.x = (u32)f2bf(a[0]) | ((u32)f2bf(a[1]) << 16);
        o.y = (u32)f2bf(a[2]) | ((u32)f2bf(a[3]) << 16);
        o.z = (u32)f2bf(b[0]) | ((u32)f2bf(b[1]) << 16);
        o.w = (u32)f2bf(b[2]) | ((u32)f2bf(b[3]) << 16);
        *(uint4*)&xb[idx] = o;
        return;
    }
    // W transpose: 48 blocks, 64x64 tiles
    __shared__ __align__(16) u16 lw[64 * LDT];
    int wb = blockIdx.x - 1024;
    int mat = wb >> 4, tile = wb & 15;
    int k0 = (tile >> 2) * 64, n0 = (tile & 3) * 64;
    const float* W = (mat == 0) ? Wq : ((mat == 1) ? Wk : Wv);
    #pragma unroll
    for (int i = 0; i < 4; ++i) {
        int c = t + 256 * i;
        int k = c >> 4, c4 = c & 15;
        f32x4 w4 = *(const f32x4*)&W[(size_t)(k0 + k) * DMODEL + n0 + c4 * 4];
        uint2 pk;
        pk.x = (u32)f2bf(w4[0]) | ((u32)f2bf(w4[1]) << 16);
        pk.y = (u32)f2bf(w4[2]) | ((u32)f2bf(w4[3]) << 16);
        *(uint2*)&lw[k * LDT + c4 * 4] = pk;
    }
    __syncthreads();
    #pragma unroll
    for (int i = 0; i < 2; ++i) {
        int c = t + 256 * i;
        int n = c >> 3, k8 = c & 7;
        union { uint4 u; u16 s[8]; } pk;
        #pragma unroll
        for (int j = 0; j < 8; ++j) pk.s[j] = lw[(k8 * 8 + j) * LDT + n];
        *(uint4*)&Wt[(size_t)mat * 65536 + (size_t)(n0 + n) * DMODEL + k0 + k8 * 8] = pk.u;
    }
}

// ---------------- kernel 0: edge (256MB int32) -> transposed bitmask (8MB) ---
// bits[nw*8192 + m]: bit i = (edge[m][nw*64+i] != 0).
// Block = 8 rows (4 waves x 2). Ballots staged in LDS; stores are full 64B lines.
__global__ __launch_bounds__(256) void k_bitmask(const int* __restrict__ edge,
                                                 u64* __restrict__ bits) {
    __shared__ u64 lb[8][128];                     // [local row][word] 8 KB
    const int t = threadIdx.x;
    const int lane = t & 63, w = t >> 6;
    const u32 m8 = blockIdx.x * 8u;
    #pragma unroll
    for (int rr = 0; rr < 2; ++rr) {
        const int mloc = w * 2 + rr;
        const size_t base = (size_t)(m8 + mloc) * NROW;
        for (int nwb = 0; nwb < 128; nwb += 16) {
            int v[16];
            #pragma unroll
            for (int j = 0; j < 16; ++j)
                v[j] = edge[base + (size_t)(nwb + j) * 64 + lane];
            u64 b[16];
            #pragma unroll
            for (int j = 0; j < 16; ++j) b[j] = __ballot(v[j] != 0);
            if (lane == 0) {
                #pragma unroll
                for (int j = 0; j < 16; ++j) lb[mloc][nwb + j] = b[j];
            }
        }
    }
    __syncthreads();
    // store: thread t -> word nw = t>>1, rows m8 + (t&1)*4 .. +3 (32B per thread,
    // two threads complete each 64B line)
    const int nw = t >> 1, mh = (t & 1) * 4;
    u64 a0 = lb[mh + 0][nw], a1 = lb[mh + 1][nw];
    u64 a2 = lb[mh + 2][nw], a3 = lb[mh + 3][nw];
    u64* dst = &bits[(size_t)nw * NROW + m8 + mh];
    uint4 p0, p1;
    p0.x = (u32)a0; p0.y = (u32)(a0 >> 32); p0.z = (u32)a1; p0.w = (u32)(a1 >> 32);
    p1.x = (u32)a2; p1.y = (u32)(a2 >> 32); p1.z = (u32)a3; p1.w = (u32)(a3 >> 32);
    *(uint4*)dst = p0;
    *(uint4*)(dst + 2) = p1;
}

// ---------------- kernel 1: QKV projections (bf16 in -> bf16 out) ----------
// blockIdx.y: 0-3 -> Q (scaled by 0.125*log2e), 4-7 -> K, 8-11 -> V (transposed)
__global__ __launch_bounds__(256, 3) void k_qkv(
    const u16* __restrict__ xb, const u16* __restrict__ Wt,
    const float* __restrict__ bq, const float* __restrict__ bk,
    const float* __restrict__ bv,
    u16* __restrict__ Qo, u16* __restrict__ Ko, u16* __restrict__ Vt) {
    __shared__ __align__(16) u16 ax[128 * LDT];
    __shared__ __align__(16) u16 wt[64 * LDT];
    const int t = threadIdx.x;
    const int lane = t & 63, wv = t >> 6;
    const int q4 = lane >> 4, l15 = lane & 15;
    const int wr = wv >> 1, wc = wv & 1;
    const int row0 = blockIdx.x * 128;
    const int mat = blockIdx.y >> 2;
    const int c0 = (blockIdx.y & 3) * 64;
    const u16* Wm = Wt + (size_t)mat * 65536;
    const float* bias = (mat == 0) ? bq : ((mat == 1) ? bk : bv);

    f32x4 acc[8];
    #pragma unroll
    for (int i = 0; i < 8; ++i) acc[i] = {0.f, 0.f, 0.f, 0.f};

    for (int kk = 0; kk < DMODEL; kk += 64) {
        #pragma unroll
        for (int i = 0; i < 4; ++i) {              // stage x tile 128x64
            int c = t + 256 * i;
            int row = c >> 3, c8 = c & 7;
            *(uint4*)&ax[row * LDT + c8 * 8] =
                *(const uint4*)&xb[(size_t)(row0 + row) * DMODEL + kk + c8 * 8];
        }
        #pragma unroll
        for (int i = 0; i < 2; ++i) {              // stage Wt tile 64(n)x64(k)
            int c = t + 256 * i;
            int n = c >> 3, c8 = c & 7;
            *(uint4*)&wt[n * LDT + c8 * 8] =
                *(const uint4*)&Wm[(size_t)(c0 + n) * DMODEL + kk + c8 * 8];
        }
        __syncthreads();
        #pragma unroll
        for (int ks = 0; ks < 2; ++ks) {
            bf16x8 xf[4], wf[2];
            #pragma unroll
            for (int it = 0; it < 4; ++it)
                xf[it] = ldb8(&ax[(wr * 64 + it * 16 + l15) * LDT + ks * 32 + q4 * 8]);
            #pragma unroll
            for (int jt = 0; jt < 2; ++jt)
                wf[jt] = ldb8(&wt[(wc * 32 + jt * 16 + l15) * LDT + ks * 32 + q4 * 8]);
            if (mat < 2) {
                #pragma unroll
                for (int it = 0; it < 4; ++it)
                    #pragma unroll
                    for (int jt = 0; jt < 2; ++jt)
                        acc[it * 2 + jt] = mfma16(xf[it], wf[jt], acc[it * 2 + jt]);
            } else {  // V: swapped operands -> D = (xW)^T
                #pragma unroll
                for (int jt = 0; jt < 2; ++jt)
                    #pragma unroll
                    for (int it = 0; it < 4; ++it)
                        acc[jt * 4 + it] = mfma16(wf[jt], xf[it], acc[jt * 4 + it]);
            }
        }
        __syncthreads();
    }

    if (mat < 2) {
        u16* out = (mat == 0) ? Qo : Ko;
        const float scale = (mat == 0) ? 0.18033688f : 1.0f;  // 0.125*log2(e)
        #pragma unroll
        for (int jt = 0; jt < 2; ++jt) {
            int col = c0 + wc * 32 + jt * 16 + l15;
            float bcol = bias[col];
            #pragma unroll
            for (int it = 0; it < 4; ++it) {
                int rowb = row0 + wr * 64 + it * 16 + q4 * 4;
                f32x4 a = acc[it * 2 + jt];
                #pragma unroll
                for (int r = 0; r < 4; ++r)
                    out[(size_t)(rowb + r) * DMODEL + col] = f2bf((a[r] + bcol) * scale);
            }
        }
    } else {
        #pragma unroll
        for (int jt = 0; jt < 2; ++jt) {
            #pragma unroll
            for (int r = 0; r < 4; ++r) {
                int drow = c0 + wc * 32 + jt * 16 + q4 * 4 + r;
                float bd = bias[drow];
                #pragma unroll
                for (int it = 0; it < 4; ++it) {
                    int col = row0 + wr * 64 + it * 16 + l15;
                    Vt[(size_t)drow * NROW + col] = f2bf(acc[jt * 4 + it][r] + bd);
                }
            }
        }
    }
}

// ---------------- kernel 2: flash attention with graph mask (R3, 162us) ----
// grid 512: h=(bid>>1)&3, qt=((bid>>3)<<1)|(bid&1) in 0..127
// BM=64 (4 waves x 16 Q-rows), BN=64; S computed TRANSPOSED (D[m][n]) so P
// packs to LDS with ds_write_b64; no-max softmax in exp2 domain; l via ones-MFMA.
// Double-buffered K/V/bits staging with register prefetch (1 barrier/iter).
__global__ __launch_bounds__(256, 2) void k_attn(
    const u16* __restrict__ Q, const u16* __restrict__ K,
    const u16* __restrict__ Vt, const u64* __restrict__ bits,
    float* __restrict__ out) {
    __shared__ __align__(16) u16 sK[2][64 * LDT];
    __shared__ __align__(16) u16 sV[2][64 * LDT];
    __shared__ __align__(16) u16 sP[4][16 * LDT];
    __shared__ __align__(16) u32 sB[2][2][64];

    const int t = threadIdx.x;
    const int lane = t & 63, w = t >> 6;
    const int q4 = lane >> 4, l15 = lane & 15;
    const int bid = blockIdx.x;
    const int h = (bid >> 1) & 3;
    const int qt = ((bid >> 3) << 1) | (bid & 1);
    const int n0 = qt * 64;
    const int half = w >> 1;
    const u32 shift = (u32)((w & 1) * 16 + l15);
    const int sr = t >> 3, sc8 = (t & 7) * 8;     // staging coords

    bf16x8 qf[2];
    #pragma unroll
    for (int ks = 0; ks < 2; ++ks)
        qf[ks] = ldb8(&Q[(size_t)(n0 + w * 16 + l15) * DMODEL + h * HD + ks * 32 + q4 * 8]);

    uint4 onesu = {0x3F803F80u, 0x3F803F80u, 0x3F803F80u, 0x3F803F80u};
    const bf16x8 ones = __builtin_bit_cast(bf16x8, onesu);

    f32x4 o[4], lacc;
    lacc = {0.f, 0.f, 0.f, 0.f};
    #pragma unroll
    for (int dt = 0; dt < 4; ++dt) o[dt] = {0.f, 0.f, 0.f, 0.f};

    uint4 rk0, rk1, rv0, rv1; uint2 rb;
    {   // prefetch + commit tile 0
        rk0 = *(const uint4*)&K[(size_t)(0 + sr) * DMODEL + h * HD + sc8];
        rk1 = *(const uint4*)&K[(size_t)(32 + sr) * DMODEL + h * HD + sc8];
        rv0 = *(const uint4*)&Vt[(size_t)(h * HD + sr) * NROW + 0 + sc8];
        rv1 = *(const uint4*)&Vt[(size_t)(h * HD + 32 + sr) * NROW + 0 + sc8];
        if (t < 64) rb = *(const uint2*)&bits[(size_t)qt * NROW + 0 + t];
        *(uint4*)&sK[0][sr * LDT + sc8] = rk0;
        *(uint4*)&sK[0][(32 + sr) * LDT + sc8] = rk1;
        *(uint4*)&sV[0][sr * LDT + sc8] = rv0;
        *(uint4*)&sV[0][(32 + sr) * LDT + sc8] = rv1;
        if (t < 64) { sB[0][0][t] = rb.x; sB[0][1][t] = rb.y; }
    }

    for (int kt = 0; kt < 128; ++kt) {
        __syncthreads();
        const int buf = kt & 1;
        if (kt < 127) {                            // issue prefetch for kt+1
            int m0 = (kt + 1) * 64;
            rk0 = *(const uint4*)&K[(size_t)(m0 + sr) * DMODEL + h * HD + sc8];
            rk1 = *(const uint4*)&K[(size_t)(m0 + 32 + sr) * DMODEL + h * HD + sc8];
            rv0 = *(const uint4*)&Vt[(size_t)(h * HD + sr) * NROW + m0 + sc8];
            rv1 = *(const uint4*)&Vt[(size_t)(h * HD + 32 + sr) * NROW + m0 + sc8];
            if (t < 64) rb = *(const uint2*)&bits[(size_t)qt * NROW + m0 + t];
        }

        f32x4 s[4];
        #pragma unroll
        for (int tj = 0; tj < 4; ++tj) s[tj] = {0.f, 0.f, 0.f, 0.f};
        #pragma unroll
        for (int ks = 0; ks < 2; ++ks) {           // S^T = K Q^T (log2 domain)
            bf16x8 kb[4];
            #pragma unroll
            for (int tj = 0; tj < 4; ++tj)
                kb[tj] = ldb8(&sK[buf][(tj * 16 + l15) * LDT + ks * 32 + q4 * 8]);
            #pragma unroll
            for (int tj = 0; tj < 4; ++tj)
                s[tj] = mfma16(kb[tj], qf[ks], s[tj]);
        }

        #pragma unroll
        for (int tj = 0; tj < 4; ++tj) {           // mask + exp2 + pack b64 -> LDS
            uint4 bw = *(const uint4*)&sB[buf][half][tj * 16 + q4 * 4];
            u32 wd[4] = {bw.x, bw.y, bw.z, bw.w};
            u32 ub[4];
            #pragma unroll
            for (int r = 0; r < 4; ++r) {
                float sv = ((wd[r] >> shift) & 1u) ? s[tj][r] : -1e30f;
                ub[r] = __builtin_bit_cast(u32, __builtin_amdgcn_exp2f(sv));
            }
            uint2 pk;
            pk.x = (ub[0] >> 16) | (ub[1] & 0xFFFF0000u);
            pk.y = (ub[2] >> 16) | (ub[3] & 0xFFFF0000u);
            *(uint2*)&sP[w][l15 * LDT + tj * 16 + q4 * 4] = pk;
        }
        asm volatile("s_waitcnt lgkmcnt(0)" ::: "memory");  // sP is wave-private

        #pragma unroll
        for (int ks = 0; ks < 2; ++ks) {           // O += P V ; l += P 1
            bf16x8 pf = ldb8(&sP[w][l15 * LDT + ks * 32 + q4 * 8]);
            bf16x8 vb[4];
            #pragma unroll
            for (int dt = 0; dt < 4; ++dt)
                vb[dt] = ldb8(&sV[buf][(dt * 16 + l15) * LDT + ks * 32 + q4 * 8]);
            #pragma unroll
            for (int dt = 0; dt < 4; ++dt)
                o[dt] = mfma16(pf, vb[dt], o[dt]);
            lacc = mfma16(pf, ones, lacc);
        }

        if (kt < 127) {                            // commit prefetched tile
            const int nb = buf ^ 1;
            *(uint4*)&sK[nb][sr * LDT + sc8] = rk0;
            *(uint4*)&sK[nb][(32 + sr) * LDT + sc8] = rk1;
            *(uint4*)&sV[nb][sr * LDT + sc8] = rv0;
            *(uint4*)&sV[nb][(32 + sr) * LDT + sc8] = rv1;
            if (t < 64) { sB[nb][0][t] = rb.x; sB[nb][1][t] = rb.y; }
        }
    }

    #pragma unroll
    for (int r = 0; r < 4; ++r) {
        float inv = __builtin_amdgcn_rcpf(lacc[r] + 1e-30f);
        int n = n0 + w * 16 + q4 * 4 + r;
        #pragma unroll
        for (int dt = 0; dt < 4; ++dt)
            out[(size_t)n * DMODEL + h * HD + dt * 16 + l15] = o[dt][r] * inv;
    }
}

extern "C" void kernel_launch(void* const* d_in, const int* in_sizes, int n_in,
                              void* d_out, int out_size, void* d_ws, size_t ws_size,
                              hipStream_t stream) {
    const float* x  = (const float*)d_in[0];
    const int* edge = (const int*)d_in[1];
    const float* Wq = (const float*)d_in[2];
    const float* bq = (const float*)d_in[3];
    const float* Wk = (const float*)d_in[4];
    const float* bk = (const float*)d_in[5];
    const float* Wv = (const float*)d_in[6];
    const float* bv = (const float*)d_in[7];

    char* ws = (char*)d_ws;
    u64* bits = (u64*)ws;                        //  8 MB
    u16* Qo  = (u16*)(ws + (8u << 20));          //  4 MB (bf16, Q pre-scaled)
    u16* Ko  = (u16*)(ws + (12u << 20));         //  4 MB (bf16)
    u16* Vt  = (u16*)(ws + (16u << 20));         //  4 MB (bf16, [256][8192])
    u16* xb  = (u16*)(ws + (20u << 20));         //  4 MB (bf16 x)
    u16* Wt  = (u16*)(ws + (24u << 20));         //  384 KB (bf16, 3x[256n][256k])
    float* out = (float*)d_out;

    hipLaunchKernelGGL(k_prep, dim3(1072), dim3(256), 0, stream, x, Wq, Wk, Wv, xb, Wt);
    hipLaunchKernelGGL(k_bitmask, dim3(1024), dim3(256), 0, stream, edge, bits);
    hipLaunchKernelGGL(k_qkv, dim3(64, 12), dim3(256), 0, stream,
                       xb, Wt, bq, bk, bv, Qo, Ko, Vt);
    hipLaunchKernelGGL(k_attn, dim3(512), dim3(256), 0, stream, Qo, Ko, Vt, bits, out);
}

// Round 7
// 516.889 us; speedup vs baseline: 1.4506x; 1.0378x over previous
//
#include <hip/hip_runtime.h>
#include <stdint.h>

typedef unsigned short u16;
typedef unsigned int u32;
typedef unsigned long long u64;

typedef __attribute__((ext_vector_type(8))) __bf16 bf16x8;
typedef __attribute__((ext_vector_type(4))) float f32x4;

#define NROW 8192
#define DMODEL 256
#define HD 64
#define LDT 72   // LDS row stride (u16) for k_qkv/k_prep tiles

__device__ __forceinline__ u16 f2bf(float f) {   // RNE f32 -> bf16
    u32 u = __builtin_bit_cast(u32, f);
    u += 0x7FFFu + ((u >> 16) & 1u);
    return (u16)(u >> 16);
}
__device__ __forceinline__ bf16x8 ldb8(const u16* p) {
    uint4 v = *(const uint4*)p;
    return __builtin_bit_cast(bf16x8, v);
}
__device__ __forceinline__ f32x4 mfma16(bf16x8 a, bf16x8 b, f32x4 c) {
    return __builtin_amdgcn_mfma_f32_16x16x32_bf16(a, b, c, 0, 0, 0);
}

// ---------------- kernel P: x f32->bf16 ; W f32->bf16 transposed -----------
__global__ __launch_bounds__(256) void k_prep(
    const float* __restrict__ x,
    const float* __restrict__ Wq, const float* __restrict__ Wk,
    const float* __restrict__ Wv,
    u16* __restrict__ xb, u16* __restrict__ Wt) {
    const int t = threadIdx.x;
    if (blockIdx.x < 1024) {                       // x convert: 8 elems/thread
        size_t idx = (size_t)blockIdx.x * 2048 + t * 8;
        f32x4 a = *(const f32x4*)&x[idx];
        f32x4 b = *(const f32x4*)&x[idx + 4];
        uint4 o;
        o.x = (u32)f2bf(a[0]) | ((u32)f2bf(a[1]) << 16);
        o.y = (u32)f2bf(a[2]) | ((u32)f2bf(a[3]) << 16);
        o.z = (u32)f2bf(b[0]) | ((u32)f2bf(b[1]) << 16);
        o.w = (u32)f2bf(b[2]) | ((u32)f2bf(b[3]) << 16);
        *(uint4*)&xb[idx] = o;
        return;
    }
    // W transpose: 48 blocks, 64x64 tiles
    __shared__ __align__(16) u16 lw[64 * LDT];
    int wb = blockIdx.x - 1024;
    int mat = wb >> 4, tile = wb & 15;
    int k0 = (tile >> 2) * 64, n0 = (tile & 3) * 64;
    const float* W = (mat == 0) ? Wq : ((mat == 1) ? Wk : Wv);
    #pragma unroll
    for (int i = 0; i < 4; ++i) {
        int c = t + 256 * i;
        int k = c >> 4, c4 = c & 15;
        f32x4 w4 = *(const f32x4*)&W[(size_t)(k0 + k) * DMODEL + n0 + c4 * 4];
        uint2 pk;
        pk.x = (u32)f2bf(w4[0]) | ((u32)f2bf(w4[1]) << 16);
        pk.y = (u32)f2bf(w4[2]) | ((u32)f2bf(w4[3]) << 16);
        *(uint2*)&lw[k * LDT + c4 * 4] = pk;
    }
    __syncthreads();
    #pragma unroll
    for (int i = 0; i < 2; ++i) {
        int c = t + 256 * i;
        int n = c >> 3, k8 = c & 7;
        union { uint4 u; u16 s[8]; } pk;
        #pragma unroll
        for (int j = 0; j < 8; ++j) pk.s[j] = lw[(k8 * 8 + j) * LDT + n];
        *(uint4*)&Wt[(size_t)mat * 65536 + (size_t)(n0 + n) * DMODEL + k0 + k8 * 8] = pk.u;
    }
}

// ---------------- kernel 0: edge (256MB int32) -> transposed bitmask (8MB) ---
// bits[nw*8192 + m]: bit i = (edge[m][nw*64+i] != 0).
// Block = 8 rows (4 waves x 2). Ballots staged in LDS; stores are full 64B lines.
__global__ __launch_bounds__(256) void k_bitmask(const int* __restrict__ edge,
                                                 u64* __restrict__ bits) {
    __shared__ u64 lb[8][128];                     // [local row][word] 8 KB
    const int t = threadIdx.x;
    const int lane = t & 63, w = t >> 6;
    const u32 m8 = blockIdx.x * 8u;
    #pragma unroll
    for (int rr = 0; rr < 2; ++rr) {
        const int mloc = w * 2 + rr;
        const size_t base = (size_t)(m8 + mloc) * NROW;
        for (int nwb = 0; nwb < 128; nwb += 16) {
            int v[16];
            #pragma unroll
            for (int j = 0; j < 16; ++j)
                v[j] = edge[base + (size_t)(nwb + j) * 64 + lane];
            u64 b[16];
            #pragma unroll
            for (int j = 0; j < 16; ++j) b[j] = __ballot(v[j] != 0);
            if (lane == 0) {
                #pragma unroll
                for (int j = 0; j < 16; ++j) lb[mloc][nwb + j] = b[j];
            }
        }
    }
    __syncthreads();
    const int nw = t >> 1, mh = (t & 1) * 4;
    u64 a0 = lb[mh + 0][nw], a1 = lb[mh + 1][nw];
    u64 a2 = lb[mh + 2][nw], a3 = lb[mh + 3][nw];
    u64* dst = &bits[(size_t)nw * NROW + m8 + mh];
    uint4 p0, p1;
    p0.x = (u32)a0; p0.y = (u32)(a0 >> 32); p0.z = (u32)a1; p0.w = (u32)(a1 >> 32);
    p1.x = (u32)a2; p1.y = (u32)(a2 >> 32); p1.z = (u32)a3; p1.w = (u32)(a3 >> 32);
    *(uint4*)dst = p0;
    *(uint4*)(dst + 2) = p1;
}

// ---------------- kernel 1: QKV projections (bf16 in -> bf16 out) ----------
// blockIdx.y: 0-3 -> Q (scaled by 0.125*log2e), 4-7 -> K, 8-11 -> V (transposed)
__global__ __launch_bounds__(256, 3) void k_qkv(
    const u16* __restrict__ xb, const u16* __restrict__ Wt,
    const float* __restrict__ bq, const float* __restrict__ bk,
    const float* __restrict__ bv,
    u16* __restrict__ Qo, u16* __restrict__ Ko, u16* __restrict__ Vt) {
    __shared__ __align__(16) u16 ax[128 * LDT];
    __shared__ __align__(16) u16 wt[64 * LDT];
    const int t = threadIdx.x;
    const int lane = t & 63, wv = t >> 6;
    const int q4 = lane >> 4, l15 = lane & 15;
    const int wr = wv >> 1, wc = wv & 1;
    const int row0 = blockIdx.x * 128;
    const int mat = blockIdx.y >> 2;
    const int c0 = (blockIdx.y & 3) * 64;
    const u16* Wm = Wt + (size_t)mat * 65536;
    const float* bias = (mat == 0) ? bq : ((mat == 1) ? bk : bv);

    f32x4 acc[8];
    #pragma unroll
    for (int i = 0; i < 8; ++i) acc[i] = {0.f, 0.f, 0.f, 0.f};

    for (int kk = 0; kk < DMODEL; kk += 64) {
        #pragma unroll
        for (int i = 0; i < 4; ++i) {              // stage x tile 128x64
            int c = t + 256 * i;
            int row = c >> 3, c8 = c & 7;
            *(uint4*)&ax[row * LDT + c8 * 8] =
                *(const uint4*)&xb[(size_t)(row0 + row) * DMODEL + kk + c8 * 8];
        }
        #pragma unroll
        for (int i = 0; i < 2; ++i) {              // stage Wt tile 64(n)x64(k)
            int c = t + 256 * i;
            int n = c >> 3, c8 = c & 7;
            *(uint4*)&wt[n * LDT + c8 * 8] =
                *(const uint4*)&Wm[(size_t)(c0 + n) * DMODEL + kk + c8 * 8];
        }
        __syncthreads();
        #pragma unroll
        for (int ks = 0; ks < 2; ++ks) {
            bf16x8 xf[4], wf[2];
            #pragma unroll
            for (int it = 0; it < 4; ++it)
                xf[it] = ldb8(&ax[(wr * 64 + it * 16 + l15) * LDT + ks * 32 + q4 * 8]);
            #pragma unroll
            for (int jt = 0; jt < 2; ++jt)
                wf[jt] = ldb8(&wt[(wc * 32 + jt * 16 + l15) * LDT + ks * 32 + q4 * 8]);
            if (mat < 2) {
                #pragma unroll
                for (int it = 0; it < 4; ++it)
                    #pragma unroll
                    for (int jt = 0; jt < 2; ++jt)
                        acc[it * 2 + jt] = mfma16(xf[it], wf[jt], acc[it * 2 + jt]);
            } else {  // V: swapped operands -> D = (xW)^T
                #pragma unroll
                for (int jt = 0; jt < 2; ++jt)
                    #pragma unroll
                    for (int it = 0; it < 4; ++it)
                        acc[jt * 4 + it] = mfma16(wf[jt], xf[it], acc[jt * 4 + it]);
            }
        }
        __syncthreads();
    }

    if (mat < 2) {
        u16* out = (mat == 0) ? Qo : Ko;
        const float scale = (mat == 0) ? 0.18033688f : 1.0f;  // 0.125*log2(e)
        #pragma unroll
        for (int jt = 0; jt < 2; ++jt) {
            int col = c0 + wc * 32 + jt * 16 + l15;
            float bcol = bias[col];
            #pragma unroll
            for (int it = 0; it < 4; ++it) {
                int rowb = row0 + wr * 64 + it * 16 + q4 * 4;
                f32x4 a = acc[it * 2 + jt];
                #pragma unroll
                for (int r = 0; r < 4; ++r)
                    out[(size_t)(rowb + r) * DMODEL + col] = f2bf((a[r] + bcol) * scale);
            }
        }
    } else {
        #pragma unroll
        for (int jt = 0; jt < 2; ++jt) {
            #pragma unroll
            for (int r = 0; r < 4; ++r) {
                int drow = c0 + wc * 32 + jt * 16 + q4 * 4 + r;
                float bd = bias[drow];
                #pragma unroll
                for (int it = 0; it < 4; ++it) {
                    int col = row0 + wr * 64 + it * 16 + l15;
                    Vt[(size_t)drow * NROW + col] = f2bf(acc[jt * 4 + it][r] + bd);
                }
            }
        }
    }
}

// ---------------- kernel 2: flash attention (R6 structure + XOR swizzle) ----
// grid 512: h=(bid>>1)&3, qt=((bid>>3)<<1)|(bid&1) in 0..127
// BM=64 (4 waves x 16 Q-rows), BN=64; S computed TRANSPOSED; no-max softmax in
// exp2 domain; l via ones-MFMA. Double-buffered staging, 1 barrier/iter.
// LDS: pad-free 64-u16 rows with chunk XOR swizzle (chunk ^= row&7).
__global__ __launch_bounds__(256, 2) void k_attn(
    const u16* __restrict__ Q, const u16* __restrict__ K,
    const u16* __restrict__ Vt, const u64* __restrict__ bits,
    float* __restrict__ out) {
    __shared__ __align__(16) u16 sK[2][64 * 64];
    __shared__ __align__(16) u16 sV[2][64 * 64];
    __shared__ __align__(16) u16 sP[4][16 * 64];
    __shared__ __align__(16) u32 sB[2][2][64];

    const int t = threadIdx.x;
    const int lane = t & 63, w = t >> 6;
    const int q4 = lane >> 4, l15 = lane & 15;
    const int l7 = l15 & 7;
    const int bid = blockIdx.x;
    const int h = (bid >> 1) & 3;
    const int qt = ((bid >> 3) << 1) | (bid & 1);
    const int n0 = qt * 64;
    const int half = w >> 1;
    const u32 shift = (u32)((w & 1) * 16 + l15);
    const int sr = t >> 3, sc = t & 7;             // staging coords
    const int ssw = (sc ^ (sr & 7)) * 8;           // swizzled chunk offset

    bf16x8 qf[2];
    #pragma unroll
    for (int ks = 0; ks < 2; ++ks)
        qf[ks] = ldb8(&Q[(size_t)(n0 + w * 16 + l15) * DMODEL + h * HD + ks * 32 + q4 * 8]);

    uint4 onesu = {0x3F803F80u, 0x3F803F80u, 0x3F803F80u, 0x3F803F80u};
    const bf16x8 ones = __builtin_bit_cast(bf16x8, onesu);

    f32x4 o[4], lacc;
    lacc = {0.f, 0.f, 0.f, 0.f};
    #pragma unroll
    for (int dt = 0; dt < 4; ++dt) o[dt] = {0.f, 0.f, 0.f, 0.f};

    uint4 rk0, rk1, rv0, rv1; uint2 rb;
    {   // prefetch + commit tile 0
        rk0 = *(const uint4*)&K[(size_t)(0 + sr) * DMODEL + h * HD + sc * 8];
        rk1 = *(const uint4*)&K[(size_t)(32 + sr) * DMODEL + h * HD + sc * 8];
        rv0 = *(const uint4*)&Vt[(size_t)(h * HD + sr) * NROW + 0 + sc * 8];
        rv1 = *(const uint4*)&Vt[(size_t)(h * HD + 32 + sr) * NROW + 0 + sc * 8];
        if (t < 64) rb = *(const uint2*)&bits[(size_t)qt * NROW + 0 + t];
        *(uint4*)&sK[0][sr * 64 + ssw] = rk0;
        *(uint4*)&sK[0][(32 + sr) * 64 + ssw] = rk1;
        *(uint4*)&sV[0][sr * 64 + ssw] = rv0;
        *(uint4*)&sV[0][(32 + sr) * 64 + ssw] = rv1;
        if (t < 64) { sB[0][0][t] = rb.x; sB[0][1][t] = rb.y; }
    }

    for (int kt = 0; kt < 128; ++kt) {
        __syncthreads();
        const int buf = kt & 1;
        if (kt < 127) {                            // issue prefetch for kt+1
            int m0 = (kt + 1) * 64;
            rk0 = *(const uint4*)&K[(size_t)(m0 + sr) * DMODEL + h * HD + sc * 8];
            rk1 = *(const uint4*)&K[(size_t)(m0 + 32 + sr) * DMODEL + h * HD + sc * 8];
            rv0 = *(const uint4*)&Vt[(size_t)(h * HD + sr) * NROW + m0 + sc * 8];
            rv1 = *(const uint4*)&Vt[(size_t)(h * HD + 32 + sr) * NROW + m0 + sc * 8];
            if (t < 64) rb = *(const uint2*)&bits[(size_t)qt * NROW + m0 + t];
        }

        f32x4 s[4];
        #pragma unroll
        for (int tj = 0; tj < 4; ++tj) s[tj] = {0.f, 0.f, 0.f, 0.f};
        #pragma unroll
        for (int ks = 0; ks < 2; ++ks) {           // S^T = K Q^T (log2 domain)
            bf16x8 kb[4];
            #pragma unroll
            for (int tj = 0; tj < 4; ++tj)
                kb[tj] = ldb8(&sK[buf][(tj * 16 + l15) * 64 + (((ks * 4 + q4) ^ l7) * 8)]);
            #pragma unroll
            for (int tj = 0; tj < 4; ++tj)
                s[tj] = mfma16(kb[tj], qf[ks], s[tj]);
        }

        #pragma unroll
        for (int tj = 0; tj < 4; ++tj) {           // mask + exp2 + pack b64 -> LDS
            uint4 bw = *(const uint4*)&sB[buf][half][tj * 16 + q4 * 4];
            u32 wd[4] = {bw.x, bw.y, bw.z, bw.w};
            u32 ub[4];
            #pragma unroll
            for (int r = 0; r < 4; ++r) {
                float sv = ((wd[r] >> shift) & 1u) ? s[tj][r] : -1e30f;
                ub[r] = __builtin_bit_cast(u32, __builtin_amdgcn_exp2f(sv));
            }
            uint2 pk;
            pk.x = (ub[0] >> 16) | (ub[1] & 0xFFFF0000u);
            pk.y = (ub[2] >> 16) | (ub[3] & 0xFFFF0000u);
            *(uint2*)&sP[w][l15 * 64 + (((tj * 2 + (q4 >> 1)) ^ l7) * 8) + (q4 & 1) * 4] = pk;
        }
        asm volatile("s_waitcnt lgkmcnt(0)" ::: "memory");  // sP is wave-private

        #pragma unroll
        for (int ks = 0; ks < 2; ++ks) {           // O += P V ; l += P 1
            bf16x8 pf = ldb8(&sP[w][l15 * 64 + (((ks * 4 + q4) ^ l7) * 8)]);
            bf16x8 vb[4];
            #pragma unroll
            for (int dt = 0; dt < 4; ++dt)
                vb[dt] = ldb8(&sV[buf][(dt * 16 + l15) * 64 + (((ks * 4 + q4) ^ l7) * 8)]);
            #pragma unroll
            for (int dt = 0; dt < 4; ++dt)
                o[dt] = mfma16(pf, vb[dt], o[dt]);
            lacc = mfma16(pf, ones, lacc);
        }

        if (kt < 127) {                            // commit prefetched tile
            const int nb = buf ^ 1;
            *(uint4*)&sK[nb][sr * 64 + ssw] = rk0;
            *(uint4*)&sK[nb][(32 + sr) * 64 + ssw] = rk1;
            *(uint4*)&sV[nb][sr * 64 + ssw] = rv0;
            *(uint4*)&sV[nb][(32 + sr) * 64 + ssw] = rv1;
            if (t < 64) { sB[nb][0][t] = rb.x; sB[nb][1][t] = rb.y; }
        }
    }

    #pragma unroll
    for (int r = 0; r < 4; ++r) {
        float inv = __builtin_amdgcn_rcpf(lacc[r] + 1e-30f);
        int n = n0 + w * 16 + q4 * 4 + r;
        #pragma unroll
        for (int dt = 0; dt < 4; ++dt)
            out[(size_t)n * DMODEL + h * HD + dt * 16 + l15] = o[dt][r] * inv;
    }
}

extern "C" void kernel_launch(void* const* d_in, const int* in_sizes, int n_in,
                              void* d_out, int out_size, void* d_ws, size_t ws_size,
                              hipStream_t stream) {
    const float* x  = (const float*)d_in[0];
    const int* edge = (const int*)d_in[1];
    const float* Wq = (const float*)d_in[2];
    const float* bq = (const float*)d_in[3];
    const float* Wk = (const float*)d_in[4];
    const float* bk = (const float*)d_in[5];
    const float* Wv = (const float*)d_in[6];
    const float* bv = (const float*)d_in[7];

    char* ws = (char*)d_ws;
    u64* bits = (u64*)ws;                        //  8 MB
    u16* Qo  = (u16*)(ws + (8u << 20));          //  4 MB (bf16, Q pre-scaled)
    u16* Ko  = (u16*)(ws + (12u << 20));         //  4 MB (bf16)
    u16* Vt  = (u16*)(ws + (16u << 20));         //  4 MB (bf16, [256][8192])
    u16* xb  = (u16*)(ws + (20u << 20));         //  4 MB (bf16 x)
    u16* Wt  = (u16*)(ws + (24u << 20));         //  384 KB (bf16, 3x[256n][256k])
    float* out = (float*)d_out;

    hipLaunchKernelGGL(k_prep, dim3(1072), dim3(256), 0, stream, x, Wq, Wk, Wv, xb, Wt);
    hipLaunchKernelGGL(k_bitmask, dim3(1024), dim3(256), 0, stream, edge, bits);
    hipLaunchKernelGGL(k_qkv, dim3(64, 12), dim3(256), 0, stream,
                       xb, Wt, bq, bk, bv, Qo, Ko, Vt);
    hipLaunchKernelGGL(k_attn, dim3(512), dim3(256), 0, stream, Qo, Ko, Vt, bits, out);
}

// Round 8
// 514.370 us; speedup vs baseline: 1.4577x; 1.0049x over previous
//
#include <hip/hip_runtime.h>
#include <stdint.h>

typedef unsigned short u16;
typedef unsigned int u32;
typedef unsigned long long u64;

typedef __attribute__((ext_vector_type(8))) __bf16 bf16x8;
typedef __attribute__((ext_vector_type(4))) float f32x4;

#define NROW 8192
#define DMODEL 256
#define HD 64
#define LDT 72   // LDS row stride (u16) for k_qkv/k_prep tiles

__device__ __forceinline__ u16 f2bf(float f) {   // RNE f32 -> bf16
    u32 u = __builtin_bit_cast(u32, f);
    u += 0x7FFFu + ((u >> 16) & 1u);
    return (u16)(u >> 16);
}
__device__ __forceinline__ bf16x8 ldb8(const u16* p) {
    uint4 v = *(const uint4*)p;
    return __builtin_bit_cast(bf16x8, v);
}
__device__ __forceinline__ f32x4 mfma16(bf16x8 a, bf16x8 b, f32x4 c) {
    return __builtin_amdgcn_mfma_f32_16x16x32_bf16(a, b, c, 0, 0, 0);
}

// ---------------- kernel P: x f32->bf16 ; W f32->bf16 transposed -----------
__global__ __launch_bounds__(256) void k_prep(
    const float* __restrict__ x,
    const float* __restrict__ Wq, const float* __restrict__ Wk,
    const float* __restrict__ Wv,
    u16* __restrict__ xb, u16* __restrict__ Wt) {
    const int t = threadIdx.x;
    if (blockIdx.x < 1024) {                       // x convert: 8 elems/thread
        size_t idx = (size_t)blockIdx.x * 2048 + t * 8;
        f32x4 a = *(const f32x4*)&x[idx];
        f32x4 b = *(const f32x4*)&x[idx + 4];
        uint4 o;
        o.x = (u32)f2bf(a[0]) | ((u32)f2bf(a[1]) << 16);
        o.y = (u32)f2bf(a[2]) | ((u32)f2bf(a[3]) << 16);
        o.z = (u32)f2bf(b[0]) | ((u32)f2bf(b[1]) << 16);
        o.w = (u32)f2bf(b[2]) | ((u32)f2bf(b[3]) << 16);
        *(uint4*)&xb[idx] = o;
        return;
    }
    // W transpose: 48 blocks, 64x64 tiles
    __shared__ __align__(16) u16 lw[64 * LDT];
    int wb = blockIdx.x - 1024;
    int mat = wb >> 4, tile = wb & 15;
    int k0 = (tile >> 2) * 64, n0 = (tile & 3) * 64;
    const float* W = (mat == 0) ? Wq : ((mat == 1) ? Wk : Wv);
    #pragma unroll
    for (int i = 0; i < 4; ++i) {
        int c = t + 256 * i;
        int k = c >> 4, c4 = c & 15;
        f32x4 w4 = *(const f32x4*)&W[(size_t)(k0 + k) * DMODEL + n0 + c4 * 4];
        uint2 pk;
        pk.x = (u32)f2bf(w4[0]) | ((u32)f2bf(w4[1]) << 16);
        pk.y = (u32)f2bf(w4[2]) | ((u32)f2bf(w4[3]) << 16);
        *(uint2*)&lw[k * LDT + c4 * 4] = pk;
    }
    __syncthreads();
    #pragma unroll
    for (int i = 0; i < 2; ++i) {
        int c = t + 256 * i;
        int n = c >> 3, k8 = c & 7;
        union { uint4 u; u16 s[8]; } pk;
        #pragma unroll
        for (int j = 0; j < 8; ++j) pk.s[j] = lw[(k8 * 8 + j) * LDT + n];
        *(uint4*)&Wt[(size_t)mat * 65536 + (size_t)(n0 + n) * DMODEL + k0 + k8 * 8] = pk.u;
    }
}

// ---------------- kernel 0: edge (256MB int32) -> transposed bitmask (8MB) ---
__global__ __launch_bounds__(256) void k_bitmask(const int* __restrict__ edge,
                                                 u64* __restrict__ bits) {
    __shared__ u64 lb[8][128];                     // [local row][word] 8 KB
    const int t = threadIdx.x;
    const int lane = t & 63, w = t >> 6;
    const u32 m8 = blockIdx.x * 8u;
    #pragma unroll
    for (int rr = 0; rr < 2; ++rr) {
        const int mloc = w * 2 + rr;
        const size_t base = (size_t)(m8 + mloc) * NROW;
        for (int nwb = 0; nwb < 128; nwb += 16) {
            int v[16];
            #pragma unroll
            for (int j = 0; j < 16; ++j)
                v[j] = edge[base + (size_t)(nwb + j) * 64 + lane];
            u64 b[16];
            #pragma unroll
            for (int j = 0; j < 16; ++j) b[j] = __ballot(v[j] != 0);
            if (lane == 0) {
                #pragma unroll
                for (int j = 0; j < 16; ++j) lb[mloc][nwb + j] = b[j];
            }
        }
    }
    __syncthreads();
    const int nw = t >> 1, mh = (t & 1) * 4;
    u64 a0 = lb[mh + 0][nw], a1 = lb[mh + 1][nw];
    u64 a2 = lb[mh + 2][nw], a3 = lb[mh + 3][nw];
    u64* dst = &bits[(size_t)nw * NROW + m8 + mh];
    uint4 p0, p1;
    p0.x = (u32)a0; p0.y = (u32)(a0 >> 32); p0.z = (u32)a1; p0.w = (u32)(a1 >> 32);
    p1.x = (u32)a2; p1.y = (u32)(a2 >> 32); p1.z = (u32)a3; p1.w = (u32)(a3 >> 32);
    *(uint4*)dst = p0;
    *(uint4*)(dst + 2) = p1;
}

// ---------------- kernel 1: QKV projections (bf16 in -> bf16 out) ----------
__global__ __launch_bounds__(256, 3) void k_qkv(
    const u16* __restrict__ xb, const u16* __restrict__ Wt,
    const float* __restrict__ bq, const float* __restrict__ bk,
    const float* __restrict__ bv,
    u16* __restrict__ Qo, u16* __restrict__ Ko, u16* __restrict__ Vt) {
    __shared__ __align__(16) u16 ax[128 * LDT];
    __shared__ __align__(16) u16 wt[64 * LDT];
    const int t = threadIdx.x;
    const int lane = t & 63, wv = t >> 6;
    const int q4 = lane >> 4, l15 = lane & 15;
    const int wr = wv >> 1, wc = wv & 1;
    const int row0 = blockIdx.x * 128;
    const int mat = blockIdx.y >> 2;
    const int c0 = (blockIdx.y & 3) * 64;
    const u16* Wm = Wt + (size_t)mat * 65536;
    const float* bias = (mat == 0) ? bq : ((mat == 1) ? bk : bv);

    f32x4 acc[8];
    #pragma unroll
    for (int i = 0; i < 8; ++i) acc[i] = {0.f, 0.f, 0.f, 0.f};

    for (int kk = 0; kk < DMODEL; kk += 64) {
        #pragma unroll
        for (int i = 0; i < 4; ++i) {
            int c = t + 256 * i;
            int row = c >> 3, c8 = c & 7;
            *(uint4*)&ax[row * LDT + c8 * 8] =
                *(const uint4*)&xb[(size_t)(row0 + row) * DMODEL + kk + c8 * 8];
        }
        #pragma unroll
        for (int i = 0; i < 2; ++i) {
            int c = t + 256 * i;
            int n = c >> 3, c8 = c & 7;
            *(uint4*)&wt[n * LDT + c8 * 8] =
                *(const uint4*)&Wm[(size_t)(c0 + n) * DMODEL + kk + c8 * 8];
        }
        __syncthreads();
        #pragma unroll
        for (int ks = 0; ks < 2; ++ks) {
            bf16x8 xf[4], wf[2];
            #pragma unroll
            for (int it = 0; it < 4; ++it)
                xf[it] = ldb8(&ax[(wr * 64 + it * 16 + l15) * LDT + ks * 32 + q4 * 8]);
            #pragma unroll
            for (int jt = 0; jt < 2; ++jt)
                wf[jt] = ldb8(&wt[(wc * 32 + jt * 16 + l15) * LDT + ks * 32 + q4 * 8]);
            if (mat < 2) {
                #pragma unroll
                for (int it = 0; it < 4; ++it)
                    #pragma unroll
                    for (int jt = 0; jt < 2; ++jt)
                        acc[it * 2 + jt] = mfma16(xf[it], wf[jt], acc[it * 2 + jt]);
            } else {  // V: swapped operands -> D = (xW)^T
                #pragma unroll
                for (int jt = 0; jt < 2; ++jt)
                    #pragma unroll
                    for (int it = 0; it < 4; ++it)
                        acc[jt * 4 + it] = mfma16(wf[jt], xf[it], acc[jt * 4 + it]);
            }
        }
        __syncthreads();
    }

    if (mat < 2) {
        u16* out = (mat == 0) ? Qo : Ko;
        const float scale = (mat == 0) ? 0.18033688f : 1.0f;  // 0.125*log2(e)
        #pragma unroll
        for (int jt = 0; jt < 2; ++jt) {
            int col = c0 + wc * 32 + jt * 16 + l15;
            float bcol = bias[col];
            #pragma unroll
            for (int it = 0; it < 4; ++it) {
                int rowb = row0 + wr * 64 + it * 16 + q4 * 4;
                f32x4 a = acc[it * 2 + jt];
                #pragma unroll
                for (int r = 0; r < 4; ++r)
                    out[(size_t)(rowb + r) * DMODEL + col] = f2bf((a[r] + bcol) * scale);
            }
        }
    } else {
        #pragma unroll
        for (int jt = 0; jt < 2; ++jt) {
            #pragma unroll
            for (int r = 0; r < 4; ++r) {
                int drow = c0 + wc * 32 + jt * 16 + q4 * 4 + r;
                float bd = bias[drow];
                #pragma unroll
                for (int it = 0; it < 4; ++it) {
                    int col = row0 + wr * 64 + it * 16 + l15;
                    Vt[(size_t)drow * NROW + col] = f2bf(acc[jt * 4 + it][r] + bd);
                }
            }
        }
    }
}

// ---------------- kernel 2: flash attention, SPLIT-K (4 slices) ------------
// grid 2048: sl=bid>>9, b9=bid&511: h=(b9>>1)&3, qt=((b9>>3)<<1)|(b9&1).
// Each block: 32 K-tiles of 64 m. No-max exp2 softmax => partials are additive.
// Writes unnormalized O^T [d][n] f32 (coalesced 64B lines) + l[64] to po.
// R7's XOR-swizzled LDS, double-buffered staging, 1 barrier/iter.
__global__ __launch_bounds__(256, 2) void k_attn(
    const u16* __restrict__ Q, const u16* __restrict__ K,
    const u16* __restrict__ Vt, const u64* __restrict__ bits,
    float* __restrict__ po) {
    __shared__ __align__(16) u16 sK[2][64 * 64];
    __shared__ __align__(16) u16 sV[2][64 * 64];
    __shared__ __align__(16) u16 sP[4][16 * 64];
    __shared__ __align__(16) u32 sB[2][2][64];

    const int t = threadIdx.x;
    const int lane = t & 63, w = t >> 6;
    const int q4 = lane >> 4, l15 = lane & 15;
    const int l7 = l15 & 7;
    const int bid = blockIdx.x;
    const int sl = bid >> 9;
    const int b9 = bid & 511;
    const int h = (b9 >> 1) & 3;
    const int qt = ((b9 >> 3) << 1) | (b9 & 1);
    const int n0 = qt * 64;
    const int mbase = sl * 2048;
    const int half = w >> 1;
    const u32 shift = (u32)((w & 1) * 16 + l15);
    const int sr = t >> 3, sc = t & 7;             // staging coords
    const int ssw = (sc ^ (sr & 7)) * 8;           // swizzled chunk offset

    bf16x8 qf[2];
    #pragma unroll
    for (int ks = 0; ks < 2; ++ks)
        qf[ks] = ldb8(&Q[(size_t)(n0 + w * 16 + l15) * DMODEL + h * HD + ks * 32 + q4 * 8]);

    uint4 onesu = {0x3F803F80u, 0x3F803F80u, 0x3F803F80u, 0x3F803F80u};
    const bf16x8 ones = __builtin_bit_cast(bf16x8, onesu);

    f32x4 o[4], lacc;
    lacc = {0.f, 0.f, 0.f, 0.f};
    #pragma unroll
    for (int dt = 0; dt < 4; ++dt) o[dt] = {0.f, 0.f, 0.f, 0.f};

    uint4 rk0, rk1, rv0, rv1; uint2 rb;
    {   // prefetch + commit tile 0 of this slice
        rk0 = *(const uint4*)&K[(size_t)(mbase + sr) * DMODEL + h * HD + sc * 8];
        rk1 = *(const uint4*)&K[(size_t)(mbase + 32 + sr) * DMODEL + h * HD + sc * 8];
        rv0 = *(const uint4*)&Vt[(size_t)(h * HD + sr) * NROW + mbase + sc * 8];
        rv1 = *(const uint4*)&Vt[(size_t)(h * HD + 32 + sr) * NROW + mbase + sc * 8];
        if (t < 64) rb = *(const uint2*)&bits[(size_t)qt * NROW + mbase + t];
        *(uint4*)&sK[0][sr * 64 + ssw] = rk0;
        *(uint4*)&sK[0][(32 + sr) * 64 + ssw] = rk1;
        *(uint4*)&sV[0][sr * 64 + ssw] = rv0;
        *(uint4*)&sV[0][(32 + sr) * 64 + ssw] = rv1;
        if (t < 64) { sB[0][0][t] = rb.x; sB[0][1][t] = rb.y; }
    }

    for (int it = 0; it < 32; ++it) {
        __syncthreads();
        const int buf = it & 1;
        if (it < 31) {                             // prefetch next tile
            int m0 = mbase + (it + 1) * 64;
            rk0 = *(const uint4*)&K[(size_t)(m0 + sr) * DMODEL + h * HD + sc * 8];
            rk1 = *(const uint4*)&K[(size_t)(m0 + 32 + sr) * DMODEL + h * HD + sc * 8];
            rv0 = *(const uint4*)&Vt[(size_t)(h * HD + sr) * NROW + m0 + sc * 8];
            rv1 = *(const uint4*)&Vt[(size_t)(h * HD + 32 + sr) * NROW + m0 + sc * 8];
            if (t < 64) rb = *(const uint2*)&bits[(size_t)qt * NROW + m0 + t];
        }

        f32x4 s[4];
        #pragma unroll
        for (int tj = 0; tj < 4; ++tj) s[tj] = {0.f, 0.f, 0.f, 0.f};
        #pragma unroll
        for (int ks = 0; ks < 2; ++ks) {           // S^T = K Q^T (log2 domain)
            bf16x8 kb[4];
            #pragma unroll
            for (int tj = 0; tj < 4; ++tj)
                kb[tj] = ldb8(&sK[buf][(tj * 16 + l15) * 64 + (((ks * 4 + q4) ^ l7) * 8)]);
            #pragma unroll
            for (int tj = 0; tj < 4; ++tj)
                s[tj] = mfma16(kb[tj], qf[ks], s[tj]);
        }

        #pragma unroll
        for (int tj = 0; tj < 4; ++tj) {           // mask + exp2 + pack b64 -> LDS
            uint4 bw = *(const uint4*)&sB[buf][half][tj * 16 + q4 * 4];
            u32 wd[4] = {bw.x, bw.y, bw.z, bw.w};
            u32 ub[4];
            #pragma unroll
            for (int r = 0; r < 4; ++r) {
                float sv = ((wd[r] >> shift) & 1u) ? s[tj][r] : -1e30f;
                ub[r] = __builtin_bit_cast(u32, __builtin_amdgcn_exp2f(sv));
            }
            uint2 pk;
            pk.x = (ub[0] >> 16) | (ub[1] & 0xFFFF0000u);
            pk.y = (ub[2] >> 16) | (ub[3] & 0xFFFF0000u);
            *(uint2*)&sP[w][l15 * 64 + (((tj * 2 + (q4 >> 1)) ^ l7) * 8) + (q4 & 1) * 4] = pk;
        }
        asm volatile("s_waitcnt lgkmcnt(0)" ::: "memory");  // sP is wave-private

        #pragma unroll
        for (int ks = 0; ks < 2; ++ks) {           // O += P V ; l += P 1
            bf16x8 pf = ldb8(&sP[w][l15 * 64 + (((ks * 4 + q4) ^ l7) * 8)]);
            bf16x8 vb[4];
            #pragma unroll
            for (int dt = 0; dt < 4; ++dt)
                vb[dt] = ldb8(&sV[buf][(dt * 16 + l15) * 64 + (((ks * 4 + q4) ^ l7) * 8)]);
            #pragma unroll
            for (int dt = 0; dt < 4; ++dt)
                o[dt] = mfma16(pf, vb[dt], o[dt]);
            lacc = mfma16(pf, ones, lacc);
        }

        if (it < 31) {                             // commit prefetched tile
            const int nb = buf ^ 1;
            *(uint4*)&sK[nb][sr * 64 + ssw] = rk0;
            *(uint4*)&sK[nb][(32 + sr) * 64 + ssw] = rk1;
            *(uint4*)&sV[nb][sr * 64 + ssw] = rv0;
            *(uint4*)&sV[nb][(32 + sr) * 64 + ssw] = rv1;
            if (t < 64) { sB[nb][0][t] = rb.x; sB[nb][1][t] = rb.y; }
        }
    }

    // partial store: O^T as [d][64 n] f32 (each lane: 4x f32x4, 64B-line coalesced)
    float* pob = po + (size_t)bid * 4160;
    #pragma unroll
    for (int dt = 0; dt < 4; ++dt)
        *(f32x4*)&pob[(dt * 16 + l15) * 64 + w * 16 + q4 * 4] = o[dt];
    if (l15 == 0) {
        #pragma unroll
        for (int r = 0; r < 4; ++r) pob[4096 + w * 16 + q4 * 4 + r] = lacc[r];
    }
}

// ---------------- kernel 3: split-K reduce + normalize ---------------------
// grid 512 (same b9 decode): sum 4 partials, divide by l, store f32 out.
__global__ __launch_bounds__(256) void k_reduce(const float* __restrict__ po,
                                                float* __restrict__ out) {
    __shared__ float sT[64 * 68];
    __shared__ float sL[64];
    const int t = threadIdx.x;
    const int b9 = blockIdx.x;
    const int h = (b9 >> 1) & 3;
    const int qt = ((b9 >> 3) << 1) | (b9 & 1);
    const int n0 = qt * 64;
    const size_t base = (size_t)b9 * 4160;
    const int d = t >> 2, ng = (t & 3) * 16;
    f32x4 a[4];
    #pragma unroll
    for (int j = 0; j < 4; ++j) a[j] = {0.f, 0.f, 0.f, 0.f};
    #pragma unroll
    for (int s = 0; s < 4; ++s) {
        const float* p = po + base + (size_t)s * (512 * 4160) + d * 64 + ng;
        #pragma unroll
        for (int j = 0; j < 4; ++j) a[j] += *(const f32x4*)&p[j * 4];
    }
    #pragma unroll
    for (int j = 0; j < 4; ++j) *(f32x4*)&sT[d * 68 + ng + j * 4] = a[j];
    if (t < 64) {
        float l = 0.f;
        #pragma unroll
        for (int s = 0; s < 4; ++s) l += po[base + (size_t)s * (512 * 4160) + 4096 + t];
        sL[t] = l;
    }
    __syncthreads();
    const int n = t >> 2, dg = (t & 3) * 16;
    float inv = __builtin_amdgcn_rcpf(sL[n] + 1e-30f);
    #pragma unroll
    for (int j = 0; j < 4; ++j) {
        f32x4 v;
        #pragma unroll
        for (int i = 0; i < 4; ++i) v[i] = sT[(dg + j * 4 + i) * 68 + n];
        v = v * inv;
        *(f32x4*)&out[(size_t)(n0 + n) * DMODEL + h * HD + dg + j * 4] = v;
    }
}

extern "C" void kernel_launch(void* const* d_in, const int* in_sizes, int n_in,
                              void* d_out, int out_size, void* d_ws, size_t ws_size,
                              hipStream_t stream) {
    const float* x  = (const float*)d_in[0];
    const int* edge = (const int*)d_in[1];
    const float* Wq = (const float*)d_in[2];
    const float* bq = (const float*)d_in[3];
    const float* Wk = (const float*)d_in[4];
    const float* bk = (const float*)d_in[5];
    const float* Wv = (const float*)d_in[6];
    const float* bv = (const float*)d_in[7];

    char* ws = (char*)d_ws;
    u64* bits = (u64*)ws;                        //  8 MB
    u16* Qo  = (u16*)(ws + (8u << 20));          //  4 MB (bf16, Q pre-scaled)
    u16* Ko  = (u16*)(ws + (12u << 20));         //  4 MB (bf16)
    u16* Vt  = (u16*)(ws + (16u << 20));         //  4 MB (bf16, [256][8192])
    u16* xb  = (u16*)(ws + (20u << 20));         //  4 MB (bf16 x)
    u16* Wt  = (u16*)(ws + (24u << 20));         //  384 KB (bf16, 3x[256n][256k])
    float* po = (float*)(ws + (32u << 20));      //  32.5 MB (split-K partials)
    float* out = (float*)d_out;

    hipLaunchKernelGGL(k_prep, dim3(1072), dim3(256), 0, stream, x, Wq, Wk, Wv, xb, Wt);
    hipLaunchKernelGGL(k_bitmask, dim3(1024), dim3(256), 0, stream, edge, bits);
    hipLaunchKernelGGL(k_qkv, dim3(64, 12), dim3(256), 0, stream,
                       xb, Wt, bq, bk, bv, Qo, Ko, Vt);
    hipLaunchKernelGGL(k_attn, dim3(2048), dim3(256), 0, stream, Qo, Ko, Vt, bits, po);
    hipLaunchKernelGGL(k_reduce, dim3(512), dim3(256), 0, stream, po, out);
}

// Round 9
// 503.401 us; speedup vs baseline: 1.4895x; 1.0218x over previous
//
#include <hip/hip_runtime.h>
#include <stdint.h>

typedef unsigned short u16;
typedef unsigned int u32;
typedef unsigned long long u64;

typedef __attribute__((ext_vector_type(8))) __bf16 bf16x8;
typedef __attribute__((ext_vector_type(4))) float f32x4;

#define NROW 8192
#define DMODEL 256
#define HD 64
#define LDT 72   // LDS row stride (u16) for k_qkv/k_prep tiles

__device__ __forceinline__ u16 f2bf(float f) {   // RNE f32 -> bf16
    u32 u = __builtin_bit_cast(u32, f);
    u += 0x7FFFu + ((u >> 16) & 1u);
    return (u16)(u >> 16);
}
__device__ __forceinline__ bf16x8 ldb8(const u16* p) {
    uint4 v = *(const uint4*)p;
    return __builtin_bit_cast(bf16x8, v);
}
__device__ __forceinline__ f32x4 mfma16(bf16x8 a, bf16x8 b, f32x4 c) {
    return __builtin_amdgcn_mfma_f32_16x16x32_bf16(a, b, c, 0, 0, 0);
}

// ---------------- kernel P: x f32->bf16 ; W f32->bf16 transposed -----------
__global__ __launch_bounds__(256) void k_prep(
    const float* __restrict__ x,
    const float* __restrict__ Wq, const float* __restrict__ Wk,
    const float* __restrict__ Wv,
    u16* __restrict__ xb, u16* __restrict__ Wt) {
    const int t = threadIdx.x;
    if (blockIdx.x < 1024) {                       // x convert: 8 elems/thread
        size_t idx = (size_t)blockIdx.x * 2048 + t * 8;
        f32x4 a = *(const f32x4*)&x[idx];
        f32x4 b = *(const f32x4*)&x[idx + 4];
        uint4 o;
        o.x = (u32)f2bf(a[0]) | ((u32)f2bf(a[1]) << 16);
        o.y = (u32)f2bf(a[2]) | ((u32)f2bf(a[3]) << 16);
        o.z = (u32)f2bf(b[0]) | ((u32)f2bf(b[1]) << 16);
        o.w = (u32)f2bf(b[2]) | ((u32)f2bf(b[3]) << 16);
        *(uint4*)&xb[idx] = o;
        return;
    }
    // W transpose: 48 blocks, 64x64 tiles
    __shared__ __align__(16) u16 lw[64 * LDT];
    int wb = blockIdx.x - 1024;
    int mat = wb >> 4, tile = wb & 15;
    int k0 = (tile >> 2) * 64, n0 = (tile & 3) * 64;
    const float* W = (mat == 0) ? Wq : ((mat == 1) ? Wk : Wv);
    #pragma unroll
    for (int i = 0; i < 4; ++i) {
        int c = t + 256 * i;
        int k = c >> 4, c4 = c & 15;
        f32x4 w4 = *(const f32x4*)&W[(size_t)(k0 + k) * DMODEL + n0 + c4 * 4];
        uint2 pk;
        pk.x = (u32)f2bf(w4[0]) | ((u32)f2bf(w4[1]) << 16);
        pk.y = (u32)f2bf(w4[2]) | ((u32)f2bf(w4[3]) << 16);
        *(uint2*)&lw[k * LDT + c4 * 4] = pk;
    }
    __syncthreads();
    #pragma unroll
    for (int i = 0; i < 2; ++i) {
        int c = t + 256 * i;
        int n = c >> 3, k8 = c & 7;
        union { uint4 u; u16 s[8]; } pk;
        #pragma unroll
        for (int j = 0; j < 8; ++j) pk.s[j] = lw[(k8 * 8 + j) * LDT + n];
        *(uint4*)&Wt[(size_t)mat * 65536 + (size_t)(n0 + n) * DMODEL + k0 + k8 * 8] = pk.u;
    }
}

// ---------------- kernel 0: edge (256MB int32) -> transposed bitmask (8MB) ---
__global__ __launch_bounds__(256) void k_bitmask(const int* __restrict__ edge,
                                                 u64* __restrict__ bits) {
    __shared__ u64 lb[8][128];                     // [local row][word] 8 KB
    const int t = threadIdx.x;
    const int lane = t & 63, w = t >> 6;
    const u32 m8 = blockIdx.x * 8u;
    #pragma unroll
    for (int rr = 0; rr < 2; ++rr) {
        const int mloc = w * 2 + rr;
        const size_t base = (size_t)(m8 + mloc) * NROW;
        for (int nwb = 0; nwb < 128; nwb += 16) {
            int v[16];
            #pragma unroll
            for (int j = 0; j < 16; ++j)
                v[j] = edge[base + (size_t)(nwb + j) * 64 + lane];
            u64 b[16];
            #pragma unroll
            for (int j = 0; j < 16; ++j) b[j] = __ballot(v[j] != 0);
            if (lane == 0) {
                #pragma unroll
                for (int j = 0; j < 16; ++j) lb[mloc][nwb + j] = b[j];
            }
        }
    }
    __syncthreads();
    const int nw = t >> 1, mh = (t & 1) * 4;
    u64 a0 = lb[mh + 0][nw], a1 = lb[mh + 1][nw];
    u64 a2 = lb[mh + 2][nw], a3 = lb[mh + 3][nw];
    u64* dst = &bits[(size_t)nw * NROW + m8 + mh];
    uint4 p0, p1;
    p0.x = (u32)a0; p0.y = (u32)(a0 >> 32); p0.z = (u32)a1; p0.w = (u32)(a1 >> 32);
    p1.x = (u32)a2; p1.y = (u32)(a2 >> 32); p1.z = (u32)a3; p1.w = (u32)(a3 >> 32);
    *(uint4*)dst = p0;
    *(uint4*)(dst + 2) = p1;
}

// ---------------- kernel 1: QKV projections (bf16 in -> bf16 out) ----------
__global__ __launch_bounds__(256, 3) void k_qkv(
    const u16* __restrict__ xb, const u16* __restrict__ Wt,
    const float* __restrict__ bq, const float* __restrict__ bk,
    const float* __restrict__ bv,
    u16* __restrict__ Qo, u16* __restrict__ Ko, u16* __restrict__ Vt) {
    __shared__ __align__(16) u16 ax[128 * LDT];
    __shared__ __align__(16) u16 wt[64 * LDT];
    const int t = threadIdx.x;
    const int lane = t & 63, wv = t >> 6;
    const int q4 = lane >> 4, l15 = lane & 15;
    const int wr = wv >> 1, wc = wv & 1;
    const int row0 = blockIdx.x * 128;
    const int mat = blockIdx.y >> 2;
    const int c0 = (blockIdx.y & 3) * 64;
    const u16* Wm = Wt + (size_t)mat * 65536;
    const float* bias = (mat == 0) ? bq : ((mat == 1) ? bk : bv);

    f32x4 acc[8];
    #pragma unroll
    for (int i = 0; i < 8; ++i) acc[i] = {0.f, 0.f, 0.f, 0.f};

    for (int kk = 0; kk < DMODEL; kk += 64) {
        #pragma unroll
        for (int i = 0; i < 4; ++i) {
            int c = t + 256 * i;
            int row = c >> 3, c8 = c & 7;
            *(uint4*)&ax[row * LDT + c8 * 8] =
                *(const uint4*)&xb[(size_t)(row0 + row) * DMODEL + kk + c8 * 8];
        }
        #pragma unroll
        for (int i = 0; i < 2; ++i) {
            int c = t + 256 * i;
            int n = c >> 3, c8 = c & 7;
            *(uint4*)&wt[n * LDT + c8 * 8] =
                *(const uint4*)&Wm[(size_t)(c0 + n) * DMODEL + kk + c8 * 8];
        }
        __syncthreads();
        #pragma unroll
        for (int ks = 0; ks < 2; ++ks) {
            bf16x8 xf[4], wf[2];
            #pragma unroll
            for (int it = 0; it < 4; ++it)
                xf[it] = ldb8(&ax[(wr * 64 + it * 16 + l15) * LDT + ks * 32 + q4 * 8]);
            #pragma unroll
            for (int jt = 0; jt < 2; ++jt)
                wf[jt] = ldb8(&wt[(wc * 32 + jt * 16 + l15) * LDT + ks * 32 + q4 * 8]);
            if (mat < 2) {
                #pragma unroll
                for (int it = 0; it < 4; ++it)
                    #pragma unroll
                    for (int jt = 0; jt < 2; ++jt)
                        acc[it * 2 + jt] = mfma16(xf[it], wf[jt], acc[it * 2 + jt]);
            } else {  // V: swapped operands -> D = (xW)^T
                #pragma unroll
                for (int jt = 0; jt < 2; ++jt)
                    #pragma unroll
                    for (int it = 0; it < 4; ++it)
                        acc[jt * 4 + it] = mfma16(wf[jt], xf[it], acc[jt * 4 + it]);
            }
        }
        __syncthreads();
    }

    if (mat < 2) {
        u16* out = (mat == 0) ? Qo : Ko;
        const float scale = (mat == 0) ? 0.18033688f : 1.0f;  // 0.125*log2(e)
        #pragma unroll
        for (int jt = 0; jt < 2; ++jt) {
            int col = c0 + wc * 32 + jt * 16 + l15;
            float bcol = bias[col];
            #pragma unroll
            for (int it = 0; it < 4; ++it) {
                int rowb = row0 + wr * 64 + it * 16 + q4 * 4;
                f32x4 a = acc[it * 2 + jt];
                #pragma unroll
                for (int r = 0; r < 4; ++r)
                    out[(size_t)(rowb + r) * DMODEL + col] = f2bf((a[r] + bcol) * scale);
            }
        }
    } else {
        #pragma unroll
        for (int jt = 0; jt < 2; ++jt) {
            #pragma unroll
            for (int r = 0; r < 4; ++r) {
                int drow = c0 + wc * 32 + jt * 16 + q4 * 4 + r;
                float bd = bias[drow];
                #pragma unroll
                for (int it = 0; it < 4; ++it) {
                    int col = row0 + wr * 64 + it * 16 + l15;
                    Vt[(size_t)drow * NROW + col] = f2bf(acc[jt * 4 + it][r] + bd);
                }
            }
        }
    }
}

// ---------------- kernel 2: flash attention, BM=128, split-K (4 slices) ----
// grid 1024: sl=bid>>8; b8=bid&255: h=b8&3, qt=b8>>2 (128 Q-rows each).
// 4 waves; each wave owns 32 Q-rows (two 16-row groups nt=0,1) -> kb/vb LDS
// reads amortized 2x. Each block: 32 K-tiles of 64 m. No-max exp2 softmax =>
// partials additive. Writes unnormalized O^T [64 d][128 n] f32 + l[128] to po.
// XOR-swizzled LDS, double-buffered staging, 1 barrier/iter.
__global__ __launch_bounds__(256, 3) void k_attn(
    const u16* __restrict__ Q, const u16* __restrict__ K,
    const u16* __restrict__ Vt, const u64* __restrict__ bits,
    float* __restrict__ po) {
    __shared__ __align__(16) u16 sK[2][64 * 64];
    __shared__ __align__(16) u16 sV[2][64 * 64];
    __shared__ __align__(16) u16 sP[4][32 * 64];
    __shared__ __align__(16) u32 sB[2][2][2][64];  // [buf][ngroup][half][m]

    const int t = threadIdx.x;
    const int lane = t & 63, w = t >> 6;
    const int q4 = lane >> 4, l15 = lane & 15;
    const int l7 = l15 & 7;
    const int bid = blockIdx.x;
    const int sl = bid >> 8;
    const int b8 = bid & 255;
    const int h = b8 & 3;
    const int qt = b8 >> 2;
    const int n0 = qt * 128;
    const int mbase = sl * 2048;
    const int half = w >> 1;
    const u32 shift = (u32)((w & 1) * 16 + l15);
    const int sr = t >> 3, sc = t & 7;             // staging coords
    const int ssw = (sc ^ (sr & 7)) * 8;           // swizzled chunk offset
    const int bg = t >> 6, bm = t & 63;            // bits staging (t<128)

    bf16x8 qf[2][2];
    #pragma unroll
    for (int nt = 0; nt < 2; ++nt)
        #pragma unroll
        for (int ks = 0; ks < 2; ++ks)
            qf[nt][ks] = ldb8(&Q[(size_t)(n0 + nt * 64 + w * 16 + l15) * DMODEL +
                                 h * HD + ks * 32 + q4 * 8]);

    uint4 onesu = {0x3F803F80u, 0x3F803F80u, 0x3F803F80u, 0x3F803F80u};
    const bf16x8 ones = __builtin_bit_cast(bf16x8, onesu);

    f32x4 o[2][4], lacc[2];
    #pragma unroll
    for (int nt = 0; nt < 2; ++nt) {
        lacc[nt] = {0.f, 0.f, 0.f, 0.f};
        #pragma unroll
        for (int dt = 0; dt < 4; ++dt) o[nt][dt] = {0.f, 0.f, 0.f, 0.f};
    }

    uint4 rk0, rk1, rv0, rv1; uint2 rb;
    {   // prefetch + commit tile 0 of this slice
        rk0 = *(const uint4*)&K[(size_t)(mbase + sr) * DMODEL + h * HD + sc * 8];
        rk1 = *(const uint4*)&K[(size_t)(mbase + 32 + sr) * DMODEL + h * HD + sc * 8];
        rv0 = *(const uint4*)&Vt[(size_t)(h * HD + sr) * NROW + mbase + sc * 8];
        rv1 = *(const uint4*)&Vt[(size_t)(h * HD + 32 + sr) * NROW + mbase + sc * 8];
        if (t < 128) rb = *(const uint2*)&bits[(size_t)(qt * 2 + bg) * NROW + mbase + bm];
        *(uint4*)&sK[0][sr * 64 + ssw] = rk0;
        *(uint4*)&sK[0][(32 + sr) * 64 + ssw] = rk1;
        *(uint4*)&sV[0][sr * 64 + ssw] = rv0;
        *(uint4*)&sV[0][(32 + sr) * 64 + ssw] = rv1;
        if (t < 128) { sB[0][bg][0][bm] = rb.x; sB[0][bg][1][bm] = rb.y; }
    }

    for (int it = 0; it < 32; ++it) {
        __syncthreads();
        const int buf = it & 1;
        if (it < 31) {                             // prefetch next tile
            int m0 = mbase + (it + 1) * 64;
            rk0 = *(const uint4*)&K[(size_t)(m0 + sr) * DMODEL + h * HD + sc * 8];
            rk1 = *(const uint4*)&K[(size_t)(m0 + 32 + sr) * DMODEL + h * HD + sc * 8];
            rv0 = *(const uint4*)&Vt[(size_t)(h * HD + sr) * NROW + m0 + sc * 8];
            rv1 = *(const uint4*)&Vt[(size_t)(h * HD + 32 + sr) * NROW + m0 + sc * 8];
            if (t < 128) rb = *(const uint2*)&bits[(size_t)(qt * 2 + bg) * NROW + m0 + bm];
        }

        f32x4 s[2][4];
        #pragma unroll
        for (int nt = 0; nt < 2; ++nt)
            #pragma unroll
            for (int tj = 0; tj < 4; ++tj) s[nt][tj] = {0.f, 0.f, 0.f, 0.f};
        #pragma unroll
        for (int ks = 0; ks < 2; ++ks) {           // S^T = K Q^T (log2 domain)
            bf16x8 kb[4];
            #pragma unroll
            for (int tj = 0; tj < 4; ++tj)
                kb[tj] = ldb8(&sK[buf][(tj * 16 + l15) * 64 + (((ks * 4 + q4) ^ l7) * 8)]);
            #pragma unroll
            for (int nt = 0; nt < 2; ++nt)
                #pragma unroll
                for (int tj = 0; tj < 4; ++tj)
                    s[nt][tj] = mfma16(kb[tj], qf[nt][ks], s[nt][tj]);
        }

        #pragma unroll
        for (int nt = 0; nt < 2; ++nt) {           // mask + exp2 + pack b64 -> LDS
            #pragma unroll
            for (int tj = 0; tj < 4; ++tj) {
                uint4 bw = *(const uint4*)&sB[buf][nt][half][tj * 16 + q4 * 4];
                u32 wd[4] = {bw.x, bw.y, bw.z, bw.w};
                u32 ub[4];
                #pragma unroll
                for (int r = 0; r < 4; ++r) {
                    float sv = ((wd[r] >> shift) & 1u) ? s[nt][tj][r] : -1e30f;
                    ub[r] = __builtin_bit_cast(u32, __builtin_amdgcn_exp2f(sv));
                }
                uint2 pk;
                pk.x = (ub[0] >> 16) | (ub[1] & 0xFFFF0000u);
                pk.y = (ub[2] >> 16) | (ub[3] & 0xFFFF0000u);
                *(uint2*)&sP[w][(nt * 16 + l15) * 64 +
                                (((tj * 2 + (q4 >> 1)) ^ l7) * 8) + (q4 & 1) * 4] = pk;
            }
        }
        asm volatile("s_waitcnt lgkmcnt(0)" ::: "memory");  // sP is wave-private

        #pragma unroll
        for (int ks = 0; ks < 2; ++ks) {           // O += P V ; l += P 1
            bf16x8 pf[2], vb[4];
            #pragma unroll
            for (int nt = 0; nt < 2; ++nt)
                pf[nt] = ldb8(&sP[w][(nt * 16 + l15) * 64 + (((ks * 4 + q4) ^ l7) * 8)]);
            #pragma unroll
            for (int dt = 0; dt < 4; ++dt)
                vb[dt] = ldb8(&sV[buf][(dt * 16 + l15) * 64 + (((ks * 4 + q4) ^ l7) * 8)]);
            #pragma unroll
            for (int nt = 0; nt < 2; ++nt) {
                #pragma unroll
                for (int dt = 0; dt < 4; ++dt)
                    o[nt][dt] = mfma16(pf[nt], vb[dt], o[nt][dt]);
                lacc[nt] = mfma16(pf[nt], ones, lacc[nt]);
            }
        }

        if (it < 31) {                             // commit prefetched tile
            const int nb = buf ^ 1;
            *(uint4*)&sK[nb][sr * 64 + ssw] = rk0;
            *(uint4*)&sK[nb][(32 + sr) * 64 + ssw] = rk1;
            *(uint4*)&sV[nb][sr * 64 + ssw] = rv0;
            *(uint4*)&sV[nb][(32 + sr) * 64 + ssw] = rv1;
            if (t < 128) { sB[nb][bg][0][bm] = rb.x; sB[nb][bg][1][bm] = rb.y; }
        }
    }

    // partial store: O^T as [64 d][128 n] f32 + l[128]
    float* pob = po + (size_t)bid * 8320;
    #pragma unroll
    for (int nt = 0; nt < 2; ++nt)
        #pragma unroll
        for (int dt = 0; dt < 4; ++dt)
            *(f32x4*)&pob[(dt * 16 + l15) * 128 + nt * 64 + w * 16 + q4 * 4] = o[nt][dt];
    if (l15 == 0) {
        #pragma unroll
        for (int nt = 0; nt < 2; ++nt)
            #pragma unroll
            for (int r = 0; r < 4; ++r)
                pob[8192 + nt * 64 + w * 16 + q4 * 4 + r] = lacc[nt][r];
    }
}

// ---------------- kernel 3: split-K reduce + normalize ---------------------
// grid 256: h=b8&3, qt=b8>>2. Sum 4 partials, divide by l, store f32 out.
__global__ __launch_bounds__(256) void k_reduce(const float* __restrict__ po,
                                                float* __restrict__ out) {
    __shared__ float sT[64 * 132];
    __shared__ float sL[128];
    const int t = threadIdx.x;
    const int b8 = blockIdx.x;
    const int h = b8 & 3;
    const int qt = b8 >> 2;
    const int n0 = qt * 128;
    const size_t base = (size_t)b8 * 8320;
    const int d = t >> 2, ng = (t & 3) * 32;
    f32x4 a[8];
    #pragma unroll
    for (int j = 0; j < 8; ++j) a[j] = {0.f, 0.f, 0.f, 0.f};
    #pragma unroll
    for (int s = 0; s < 4; ++s) {
        const float* p = po + base + (size_t)s * (256 * 8320) + d * 128 + ng;
        #pragma unroll
        for (int j = 0; j < 8; ++j) a[j] += *(const f32x4*)&p[j * 4];
    }
    #pragma unroll
    for (int j = 0; j < 8; ++j) *(f32x4*)&sT[d * 132 + ng + j * 4] = a[j];
    if (t < 128) {
        float l = 0.f;
        #pragma unroll
        for (int s = 0; s < 4; ++s) l += po[base + (size_t)s * (256 * 8320) + 8192 + t];
        sL[t] = l;
    }
    __syncthreads();
    const int n = t >> 1, dg = (t & 1) * 32;
    float inv = __builtin_amdgcn_rcpf(sL[n] + 1e-30f);
    #pragma unroll
    for (int j = 0; j < 8; ++j) {
        f32x4 v;
        #pragma unroll
        for (int i = 0; i < 4; ++i) v[i] = sT[(dg + j * 4 + i) * 132 + n];
        v = v * inv;
        *(f32x4*)&out[(size_t)(n0 + n) * DMODEL + h * HD + dg + j * 4] = v;
    }
}

extern "C" void kernel_launch(void* const* d_in, const int* in_sizes, int n_in,
                              void* d_out, int out_size, void* d_ws, size_t ws_size,
                              hipStream_t stream) {
    const float* x  = (const float*)d_in[0];
    const int* edge = (const int*)d_in[1];
    const float* Wq = (const float*)d_in[2];
    const float* bq = (const float*)d_in[3];
    const float* Wk = (const float*)d_in[4];
    const float* bk = (const float*)d_in[5];
    const float* Wv = (const float*)d_in[6];
    const float* bv = (const float*)d_in[7];

    char* ws = (char*)d_ws;
    u64* bits = (u64*)ws;                        //  8 MB
    u16* Qo  = (u16*)(ws + (8u << 20));          //  4 MB (bf16, Q pre-scaled)
    u16* Ko  = (u16*)(ws + (12u << 20));         //  4 MB (bf16)
    u16* Vt  = (u16*)(ws + (16u << 20));         //  4 MB (bf16, [256][8192])
    u16* xb  = (u16*)(ws + (20u << 20));         //  4 MB (bf16 x)
    u16* Wt  = (u16*)(ws + (24u << 20));         //  384 KB (bf16, 3x[256n][256k])
    float* po = (float*)(ws + (32u << 20));      //  34 MB (split-K partials)
    float* out = (float*)d_out;

    hipLaunchKernelGGL(k_prep, dim3(1072), dim3(256), 0, stream, x, Wq, Wk, Wv, xb, Wt);
    hipLaunchKernelGGL(k_bitmask, dim3(1024), dim3(256), 0, stream, edge, bits);
    hipLaunchKernelGGL(k_qkv, dim3(64, 12), dim3(256), 0, stream,
                       xb, Wt, bq, bk, bv, Qo, Ko, Vt);
    hipLaunchKernelGGL(k_attn, dim3(1024), dim3(256), 0, stream, Qo, Ko, Vt, bits, po);
    hipLaunchKernelGGL(k_reduce, dim3(256), dim3(256), 0, stream, po, out);
}